// Round 1
// 429.743 us; speedup vs baseline: 1.0637x; 1.0637x over previous
//
#include <hip/hip_runtime.h>

// ---------------------------------------------------------------------------
// SlidingWindowAttention — fp32 in/out.
// Logit path: bf16 hi/lo 3-term MFMA. Split uses INTEGER RNE (immune to
// fp-contraction). Value path: fp16 (V-proj, P, V, AO, out-proj).
//
// gemm_qk2: 256x256 tile, BK=32, 512 thr (8 waves 2m x 4n), dbuf LDS 128KB,
// staggered 3-term phases with counted vmcnt (never 0 in loop), raw s_barrier,
// XOR bank-swizzle on A/B tiles, setprio around MFMA clusters, XCD-chunked
// block swizzle. A split in-GEMM (regs->LDS), B pre-split staged via dma16
// with pre-swizzled per-lane global source.
//
// ws (96 MB): QP[0,32) fp32->packed hi/lo | KP[32,64) | VT fp16 [64,80) |
//             AO fp16 [80,96)
// d_out used as scratch for pre-split weights (first 10 MB), overwritten by
// the final out-projection (sole writer of d_out).
// ---------------------------------------------------------------------------

typedef __attribute__((ext_vector_type(8))) short short8v;
typedef __attribute__((ext_vector_type(4))) float float4v;
typedef __attribute__((ext_vector_type(8))) _Float16 half8v;

#define MFMA_BF16(A_, B_, C_) __builtin_amdgcn_mfma_f32_16x16x32_bf16((A_), (B_), (C_), 0, 0, 0)
#define MFMA_F16(A_, B_, C_)  __builtin_amdgcn_mfma_f32_16x16x32_f16((A_), (B_), (C_), 0, 0, 0)

#define VMW_(n) asm volatile("s_waitcnt vmcnt(" #n ")" ::: "memory")
#define VMW(n) VMW_(n)
#define LGKM0 asm volatile("s_waitcnt lgkmcnt(0)" ::: "memory")
#define BARF do { __builtin_amdgcn_s_barrier(); asm volatile("" ::: "memory"); } while (0)

// hi = RNE(x -> bf16) via INTEGER rounding (cannot be contracted/fused);
// lo = x - hi exact in fp32; packed by truncation (err <= 2^-17 |x|).
__device__ __forceinline__ void split_rn(float x, short& h, short& l) {
    unsigned int u = __float_as_uint(x);
    u += 0x7fffu + ((u >> 16) & 1u);          // RNE in integer domain
    unsigned int hb = u & 0xffff0000u;
    h = (short)(hb >> 16);
    float lo = x - __uint_as_float(hb);       // exact (Sterbenz-ish, hi near x)
    l = (short)(__float_as_uint(lo) >> 16);   // truncate lo to bf16
}

// async 16B global -> LDS (wave-uniform LDS base + lane*16)
__device__ __forceinline__ void dma16(const void* g, void* l) {
    __builtin_amdgcn_global_load_lds(
        (__attribute__((address_space(1))) void*)g,
        (__attribute__((address_space(3))) void*)l, 16, 0, 0);
}

// ---------------- prep: weight splits/cvts into d_out scratch ----------------
// scr ushort layout: [0,1M)=wqh [1M,2M)=wql [2M,3M)=wkh [3M,4M)=wkl [4M,5M)=wv16
__global__ __launch_bounds__(256) void prep_k(
    const float* __restrict__ wq, const float* __restrict__ wk,
    const float* __restrict__ wv, unsigned short* __restrict__ scr)
{
    const int M1 = 1 << 20;
    unsigned int tid = blockIdx.x * 256 + threadIdx.x;   // 0 .. 3M-1
    if (tid < (unsigned)M1) {
        short h, l; split_rn(wq[tid], h, l);
        scr[tid] = (unsigned short)h;
        scr[M1 + tid] = (unsigned short)l;
    } else if (tid < (unsigned)(2 * M1)) {
        unsigned int i = tid - M1;
        short h, l; split_rn(wk[i], h, l);
        scr[2 * M1 + i] = (unsigned short)h;
        scr[3 * M1 + i] = (unsigned short)l;
    } else {
        unsigned int i = tid - 2 * M1;
        scr[4 * M1 + i] = __builtin_bit_cast(unsigned short, (_Float16)wv[i]);
    }
}

// ---------------- Q/K projection: C = A * B^T, 3-term bf16 hi/lo ----------------
// 256x256 tile, BK=32, staggered counted-vmcnt schedule (see header).
__global__ __launch_bounds__(512, 2) void gemm_qk2(
    const float* __restrict__ A0, const short* __restrict__ Bh0,
    const short* __restrict__ Bl0, float* __restrict__ C0,
    const float* __restrict__ A1, const short* __restrict__ Bh1,
    const short* __restrict__ Bl1, float* __restrict__ C1)
{
    // LDS: slot p at p*32768 shorts. Within slot (shorts):
    //   Ah +0, Al +8192, Bh +16384, Bl +24576; each array 256 rows x 32 cols.
    __shared__ __align__(16) short S[2 * 32768];   // 128 KiB

    // XCD-chunked swizzle: consecutive cid share an XCD; cid -> (z, m, n) with
    // the 4 n-blocks of one A-stripe adjacent (L2 A-reuse within XCD).
    const int bid = blockIdx.x;                 // grid = 256 exactly
    const int cid = ((bid & 7) << 5) | (bid >> 3);
    const int z   = cid >> 7;
    const int rem = cid & 127;
    const int bm  = (rem >> 2) << 8;            // 32 m-blocks * 256
    const int bn  = (rem & 3) << 8;             // 4 n-blocks * 256

    const float* Ap  = z ? A1  : A0;
    const short* Bhp = z ? Bh1 : Bh0;
    const short* Blp = z ? Bl1 : Bl0;
    float*       Cp  = z ? C1  : C0;

    const int t = threadIdx.x;
    const int wave = t >> 6, lane = t & 63;
    const int c16 = lane & 15, quad = lane >> 4;
    const int wm = (wave >> 2) << 7;            // 0 / 128
    const int wn = (wave & 3) << 6;             // 0 / 64 / 128 / 192

    // A staging: thread covers row ar, 16 cols (half-row) -> 2 swizzled 8-chunks
    const int ar = t >> 1;                      // 0..255
    const int ah16 = (t & 1) << 4;
    const int fA = (ar & 3) ^ ((ar >> 2) & 3);
    const int swA0 = ((((t & 1) << 1) | 0) ^ fA) << 3;   // shorts
    const int swA1 = ((((t & 1) << 1) | 1) ^ fA) << 3;

    // B dma: lane covers row (32*wave + 16*g + br), pre-swizzled source slot
    const int br  = lane >> 2;                  // 0..15
    const int fsl = (((lane & 3) ^ ((br & 3) ^ ((br >> 2) & 3))) << 3); // shorts

    // fragment read slot (swizzled): wanted slot = quad, row&15 = c16
    const int frd = ((quad ^ ((c16 & 3) ^ ((c16 >> 2) & 3))) << 3);     // shorts

    float4v acc[8][4];
#pragma unroll
    for (int i = 0; i < 8; i++)
#pragma unroll
        for (int j = 0; j < 4; j++) acc[i][j] = (float4v){0.f, 0.f, 0.f, 0.f};

#define STAGE_B(pp, kk)                                                          \
    do {                                                                         \
        const size_t rb = (size_t)(bn + (wave << 5) + br) * 1024 + (kk) + fsl;   \
        short* dh = S + (pp) * 32768 + 16384 + (wave << 10);                     \
        short* dl = dh + 8192;                                                   \
        dma16(Bhp + rb,             dh);                                         \
        dma16(Bhp + rb + 16 * 1024, dh + 512);                                   \
        dma16(Blp + rb,             dl);                                         \
        dma16(Blp + rb + 16 * 1024, dl + 512);                                   \
    } while (0)

    // prologue: A(0) regs first (oldest in vmcnt queue), then B(0) dma -> slot 0
    const float* arow = Ap + (size_t)(bm + ar) * 1024 + ah16;
    float4v ap0 = *(const float4v*)(arow + 0);
    float4v ap1 = *(const float4v*)(arow + 4);
    float4v ap2 = *(const float4v*)(arow + 8);
    float4v ap3 = *(const float4v*)(arow + 12);
    STAGE_B(0, 0);

#define SPLIT_WRITE(sp_)                                                         \
    do {                                                                         \
        short8v h0, l0, h1, l1;                                                  \
        _Pragma("unroll")                                                        \
        for (int jj = 0; jj < 4; jj++) {                                         \
            short hh, ll;                                                        \
            split_rn(ap0[jj], hh, ll); h0[jj] = hh;     l0[jj] = ll;             \
            split_rn(ap1[jj], hh, ll); h0[jj + 4] = hh; l0[jj + 4] = ll;         \
            split_rn(ap2[jj], hh, ll); h1[jj] = hh;     l1[jj] = ll;             \
            split_rn(ap3[jj], hh, ll); h1[jj + 4] = hh; l1[jj + 4] = ll;         \
        }                                                                        \
        short* abase = (sp_) + ar * 32;                                          \
        *(short8v*)(abase + swA0) = h0;                                          \
        *(short8v*)(abase + swA1) = h1;                                          \
        *(short8v*)(abase + 8192 + swA0) = l0;                                   \
        *(short8v*)(abase + 8192 + swA1) = l1;                                   \
    } while (0)

#define LOAD_AH_BH(sp_)                                                          \
    _Pragma("unroll")                                                            \
    for (int i = 0; i < 8; i++)                                                  \
        ah[i] = *(const short8v*)((sp_) + (wm + i * 16 + c16) * 32 + frd);       \
    _Pragma("unroll")                                                            \
    for (int j = 0; j < 4; j++)                                                  \
        bh[j] = *(const short8v*)((sp_) + 16384 + (wn + j * 16 + c16) * 32 + frd)

#define MFMA_CLUSTER(AARR, BARR)                                                 \
    do {                                                                         \
        __builtin_amdgcn_s_setprio(1);                                           \
        _Pragma("unroll")                                                        \
        for (int i = 0; i < 8; i++)                                              \
            _Pragma("unroll")                                                    \
            for (int j = 0; j < 4; j++)                                          \
                acc[i][j] = MFMA_BF16(AARR[i & 7], BARR[j & 3], acc[i][j]);      \
        __builtin_amdgcn_s_setprio(0);                                           \
    } while (0)

    int kb = 0;
#pragma unroll 1
    for (int tt = 0; tt < 31; ++tt, kb += 32) {
        const int p = tt & 1;
        short* sp = S + p * 32768;

        // S1: A(t) regs done -> split -> LDS slot p; issue A(t+1) reg loads
        VMW(4);
        SPLIT_WRITE(sp);
        ap0 = *(const float4v*)(arow + kb + 32);
        ap1 = *(const float4v*)(arow + kb + 36);
        ap2 = *(const float4v*)(arow + kb + 40);
        ap3 = *(const float4v*)(arow + kb + 44);
        LGKM0;
        BARF;                       // A(t) visible; all t-1 readers of slot p^1 done
        STAGE_B(p ^ 1, kb + 32);    // B(t+1) dma -> other slot
        VMW(10);                    // own Bh(t) landed (Bl(t)+A(t+1)+B(t+1)=10 in flight)
        BARF;                       // everyone's Bh(t) visible
        // PH1: hi*hi
        short8v ah[8], bh[4];
        LOAD_AH_BH(sp);
        MFMA_CLUSTER(ah, bh);
        VMW(8);                     // own Bl(t) landed (A(t+1)+B(t+1)=8 in flight)
        BARF;
        // PH2: Ah*Bl (ah kept in regs)
        {
            short8v bl[4];
#pragma unroll
            for (int j = 0; j < 4; j++)
                bl[j] = *(const short8v*)(sp + 24576 + (wn + j * 16 + c16) * 32 + frd);
            MFMA_CLUSTER(ah, bl);
        }
        // PH3: Al*Bh (bh kept in regs)
        {
            short8v al[8];
#pragma unroll
            for (int i = 0; i < 8; i++)
                al[i] = *(const short8v*)(sp + 8192 + (wm + i * 16 + c16) * 32 + frd);
            MFMA_CLUSTER(al, bh);
        }
    }

    // peeled last tile (tt = 31, p = 1): no prefetch, drain waits
    {
        short* sp = S + 32768;
        VMW(4);
        SPLIT_WRITE(sp);
        LGKM0;
        BARF;
        VMW(2);                     // Bh(31) landed
        BARF;
        short8v ah[8], bh[4];
        LOAD_AH_BH(sp);
        MFMA_CLUSTER(ah, bh);
        VMW(0);                     // Bl(31) landed
        BARF;
        {
            short8v bl[4];
#pragma unroll
            for (int j = 0; j < 4; j++)
                bl[j] = *(const short8v*)(sp + 24576 + (wn + j * 16 + c16) * 32 + frd);
            MFMA_CLUSTER(ah, bl);
        }
        {
            short8v al[8];
#pragma unroll
            for (int i = 0; i < 8; i++)
                al[i] = *(const short8v*)(sp + 8192 + (wm + i * 16 + c16) * 32 + frd);
            MFMA_CLUSTER(al, bh);
        }
    }

#undef STAGE_B
#undef SPLIT_WRITE
#undef LOAD_AH_BH
#undef MFMA_CLUSTER

    // epilogue: C/D 16x16: row = quad*4 + r, col = c16
#pragma unroll
    for (int i = 0; i < 8; i++) {
        const size_t gr0 = (size_t)(bm + wm + i * 16 + quad * 4);
#pragma unroll
        for (int j = 0; j < 4; j++) {
            const int gc = bn + wn + j * 16 + c16;
#pragma unroll
            for (int r = 0; r < 4; r++)
                Cp[(gr0 + r) * 1024 + gc] = acc[i][j][r];
        }
    }
}

// ---------------- fp16 GEMM (V-proj / out-proj), C = A * B^T ----------------
// AF16/BF16: operand already fp16 -> DMA staging; else fp32 + cvt.
// OMODE 0: store fp16 VT transposed. OMODE 1: fp32 + bias -> Cp.
template <int AF16, int BF16, int OMODE>
__global__ __launch_bounds__(256) void gemm16(
    const void* __restrict__ Ap, const void* __restrict__ Bp,
    void* __restrict__ Cp, const float* __restrict__ bias)
{
    const int N = 1024, K = 1024;

    __shared__ __align__(16) short As[128 * 32];
    __shared__ __align__(16) short Bs[128 * 32];

    const int t = threadIdx.x;
    const int bm = blockIdx.y << 7;
    const int bn = blockIdx.x << 7;
    const int lane = t & 63;
    const int wave = t >> 6;
    const int wm = (wave >> 1) << 6;
    const int wn = (wave & 1) << 6;
    const int c16 = lane & 15;
    const int quad = lane >> 4;
    const int lr = t >> 2;
    const int lc = (t & 3) << 3;

    float4v acc[4][4];
#pragma unroll
    for (int i = 0; i < 4; i++)
#pragma unroll
        for (int j = 0; j < 4; j++) acc[i][j] = (float4v){0.f, 0.f, 0.f, 0.f};

    for (int kb = 0; kb < K; kb += 32) {
        if (AF16) {
            const _Float16* Af = (const _Float16*)Ap;
#pragma unroll
            for (int g = 0; g < 2; g++)
                dma16(Af + (size_t)(bm + g * 64 + lr) * K + kb + lc,
                      As + g * 2048 + wave * 512);
        } else {
            const float* Af = (const float*)Ap;
#pragma unroll
            for (int g = 0; g < 2; g++) {
                const float* src = Af + (size_t)(bm + g * 64 + lr) * K + kb + lc;
                float4v f0 = *(const float4v*)src;
                float4v f1 = *(const float4v*)(src + 4);
                half8v h;
#pragma unroll
                for (int j = 0; j < 8; j++) h[j] = (_Float16)((j < 4) ? f0[j] : f1[j - 4]);
                *(half8v*)(As + (g * 64 + lr) * 32 + lc) = h;
            }
        }
        if (BF16) {
            const _Float16* Bf = (const _Float16*)Bp;
#pragma unroll
            for (int g = 0; g < 2; g++)
                dma16(Bf + (size_t)(bn + g * 64 + lr) * K + kb + lc,
                      Bs + g * 2048 + wave * 512);
        } else {
            const float* Bf = (const float*)Bp;
#pragma unroll
            for (int g = 0; g < 2; g++) {
                const float* src = Bf + (size_t)(bn + g * 64 + lr) * K + kb + lc;
                float4v f0 = *(const float4v*)src;
                float4v f1 = *(const float4v*)(src + 4);
                half8v h;
#pragma unroll
                for (int j = 0; j < 8; j++) h[j] = (_Float16)((j < 4) ? f0[j] : f1[j - 4]);
                *(half8v*)(Bs + (g * 64 + lr) * 32 + lc) = h;
            }
        }
        __syncthreads();

        half8v ah[4], bh[4];
#pragma unroll
        for (int i = 0; i < 4; i++)
            ah[i] = *(const half8v*)(As + (wm + i * 16 + c16) * 32 + quad * 8);
#pragma unroll
        for (int j = 0; j < 4; j++)
            bh[j] = *(const half8v*)(Bs + (wn + j * 16 + c16) * 32 + quad * 8);
#pragma unroll
        for (int i = 0; i < 4; i++)
#pragma unroll
            for (int j = 0; j < 4; j++)
                acc[i][j] = MFMA_F16(ah[i], bh[j], acc[i][j]);
        __syncthreads();
    }

#pragma unroll
    for (int i = 0; i < 4; i++)
#pragma unroll
        for (int j = 0; j < 4; j++)
#pragma unroll
            for (int r = 0; r < 4; r++) {
                int gr = bm + wm + i * 16 + quad * 4 + r;
                int gc = bn + wn + j * 16 + c16;
                float vv = acc[i][j][r];
                if (OMODE == 0) {
                    ((unsigned short*)Cp)[((size_t)(gc << 1) + (gr >> 12)) * 4096 + (gr & 4095)] =
                        __builtin_bit_cast(unsigned short, (_Float16)vv);
                } else {
                    ((float*)Cp)[(size_t)gr * N + gc] = vv + bias[gc];
                }
            }
}

// ---------------- RoPE + in-place hi/lo pack, 4 rows share sincos ----------------
__global__ __launch_bounds__(256) void rope_pack(float* __restrict__ QP, float* __restrict__ KP)
{
    int sp = blockIdx.x;            // 0..4095
    int t = threadIdx.x;
    float* rows[4] = { QP + ((size_t)sp << 10), QP + ((size_t)(4096 + sp) << 10),
                       KP + ((size_t)sp << 10), KP + ((size_t)(4096 + sp) << 10) };

    float c[2], sn[2];
    float x1[4][2], x2[4][2];
#pragma unroll
    for (int p = 0; p < 2; p++) {
        int j = t + p * 256;
        float freq = __expf(-0.017988946f * (float)j);   // 10000^(-j/512)
        float ang = (float)sp * freq;
        sincosf(ang, &sn[p], &c[p]);
#pragma unroll
        for (int r = 0; r < 4; r++) {
            x1[r][p] = rows[r][j];
            x2[r][p] = rows[r][j + 512];
        }
    }
    __syncthreads();
#pragma unroll
    for (int r = 0; r < 4; r++) {
        unsigned short* u = (unsigned short*)rows[r];
#pragma unroll
        for (int p = 0; p < 2; p++) {
            int j = t + p * 256;
            float y1 = x1[r][p] * c[p] - x2[r][p] * sn[p];
            float y2 = x1[r][p] * sn[p] + x2[r][p] * c[p];
            short h1, l1, h2, l2;
            split_rn(y1, h1, l1);
            split_rn(y2, h2, l2);
            u[j] = (unsigned short)h1;
            u[j + 512] = (unsigned short)h2;
            u[1024 + j] = (unsigned short)l1;
            u[1024 + j + 512] = (unsigned short)l2;
        }
    }
}

// ---------------- Banded attention ----------------
// QK^T: bf16 hi/lo 3-term from packed QP/KP. PV: fp16 (P scaled x512).
__global__ __launch_bounds__(256) void attn_k(
    const unsigned short* __restrict__ QHL, const unsigned short* __restrict__ KHL,
    const unsigned short* __restrict__ VT, unsigned short* __restrict__ AO)
{
    const int S = 4096;
    const float NEG = -1e30f;
    const float PSC = 512.0f;
    const int bq = blockIdx.x, h = blockIdx.y, b = blockIdx.z;
    const int t = threadIdx.x;
    const int wave = t >> 6, lane = t & 63;
    const int col = lane & 15, quad = lane >> 4;
    const int qg = (bq << 6) + (wave << 4);

    __shared__ __align__(16) short Khs[64 * 72];
    __shared__ __align__(16) short Kls[64 * 72];
    __shared__ __align__(16) short Vs[64 * 72];
    __shared__ __align__(16) short Ps[4][16 * 72];
    short* myP = &Ps[wave][0];

    const int sk = t >> 3;        // 0..31
    const int sd = (t & 7) << 3;  // 0..56 step 8

    short8v qh[2], ql[2];
    {
        const unsigned short* qr = QHL + ((size_t)(b * S + qg + col) << 11) + h * 64 + quad * 8;
        qh[0] = *(const short8v*)(qr);
        qh[1] = *(const short8v*)(qr + 32);
        ql[0] = *(const short8v*)(qr + 1024);
        ql[1] = *(const short8v*)(qr + 1024 + 32);
    }

    float mrun[4], lrun[4];
    float4v O[4];
#pragma unroll
    for (int r = 0; r < 4; r++) { mrun[r] = NEG; lrun[r] = 0.f; }
#pragma unroll
    for (int t4 = 0; t4 < 4; t4++) O[t4] = (float4v){0.f, 0.f, 0.f, 0.f};

    const int blk0 = bq << 6;
    const int kstart = (blk0 - 256 > 0) ? (blk0 - 256) : 0;
    const int kend = (blk0 + 320 < S) ? (blk0 + 320) : S;

    for (int kb = kstart; kb < kend; kb += 64) {
#pragma unroll
        for (int p = 0; p < 2; p++) {
            int key = p * 32 + sk;
            const unsigned short* krow = KHL + ((size_t)(b * S + kb + key) << 11) + h * 64 + sd;
            *(short8v*)(Khs + key * 72 + sd) = *(const short8v*)krow;
            *(short8v*)(Kls + key * 72 + sd) = *(const short8v*)(krow + 1024);
            int dm = p * 32 + sk;
            const unsigned short* vrow = VT + ((size_t)((h * 64 + dm) << 1) + b) * S + kb + sd;
            *(short8v*)(Vs + dm * 72 + sd) = *(const short8v*)vrow;
        }
        __syncthreads();

        float4v sv[4];
#pragma unroll
        for (int c = 0; c < 4; c++) {
            const short* kro = Khs + (c * 16 + col) * 72 + quad * 8;
            const short* klo = Kls + (c * 16 + col) * 72 + quad * 8;
            short8v kh0 = *(const short8v*)kro;
            short8v kh1 = *(const short8v*)(kro + 32);
            short8v kl0 = *(const short8v*)klo;
            short8v kl1 = *(const short8v*)(klo + 32);
            float4v sc = (float4v){0.f, 0.f, 0.f, 0.f};
            sc = MFMA_BF16(qh[0], kh0, sc);
            sc = MFMA_BF16(qh[1], kh1, sc);
            sc = MFMA_BF16(qh[0], kl0, sc);
            sc = MFMA_BF16(qh[1], kl1, sc);
            sc = MFMA_BF16(ql[0], kh0, sc);
            sc = MFMA_BF16(ql[1], kh1, sc);
            sv[c] = sc;
        }

        float mx[4], alpha[4], psum[4];
#pragma unroll
        for (int r = 0; r < 4; r++) {
            int qrow = qg + quad * 4 + r;
            float m = NEG;
#pragma unroll
            for (int c = 0; c < 4; c++) {
                int key = kb + c * 16 + col;
                float vv = (key >= qrow - 256 && key <= qrow + 256) ? sv[c][r] * 8.0f : NEG;
                sv[c][r] = vv;
                m = fmaxf(m, vv);
            }
            mx[r] = m;
        }
#pragma unroll
        for (int st = 1; st < 16; st <<= 1)
#pragma unroll
            for (int r = 0; r < 4; r++) mx[r] = fmaxf(mx[r], __shfl_xor(mx[r], st, 64));

#pragma unroll
        for (int r = 0; r < 4; r++) {
            float mn = fmaxf(mrun[r], mx[r]);
            alpha[r] = __expf(mrun[r] - mn);
            mrun[r] = mn;
            float ps = 0.f;
#pragma unroll
            for (int c = 0; c < 4; c++) {
                float p = __expf(sv[c][r] - mn);
                ps += p;
                myP[(quad * 4 + r) * 72 + c * 16 + col] =
                    __builtin_bit_cast(short, (_Float16)(p * PSC));
            }
            psum[r] = ps;
        }
#pragma unroll
        for (int st = 1; st < 16; st <<= 1)
#pragma unroll
            for (int r = 0; r < 4; r++) psum[r] += __shfl_xor(psum[r], st, 64);
#pragma unroll
        for (int r = 0; r < 4; r++) lrun[r] = lrun[r] * alpha[r] + psum[r];
#pragma unroll
        for (int t4 = 0; t4 < 4; t4++)
#pragma unroll
            for (int r = 0; r < 4; r++) O[t4][r] *= alpha[r];

#pragma unroll
        for (int kf = 0; kf < 2; kf++) {
            half8v pa = *(const half8v*)(myP + col * 72 + kf * 32 + quad * 8);
#pragma unroll
            for (int t4 = 0; t4 < 4; t4++) {
                half8v vb = *(const half8v*)(Vs + (t4 * 16 + col) * 72 + kf * 32 + quad * 8);
                O[t4] = MFMA_F16(pa, vb, O[t4]);
            }
        }
        __syncthreads();
    }

#pragma unroll
    for (int r = 0; r < 4; r++) {
        float inv = (lrun[r] > 0.f) ? (1.0f / (lrun[r] * PSC)) : 0.f;
        unsigned short* orow = AO + (size_t)(b * S + qg + quad * 4 + r) * 1024 + h * 64;
#pragma unroll
        for (int t4 = 0; t4 < 4; t4++)
            orow[t4 * 16 + col] = __builtin_bit_cast(unsigned short, (_Float16)(O[t4][r] * inv));
    }
}

extern "C" void kernel_launch(void* const* d_in, const int* in_sizes, int n_in,
                              void* d_out, int out_size, void* d_ws, size_t ws_size,
                              hipStream_t stream) {
    const float* q   = (const float*)d_in[0];
    const float* k   = (const float*)d_in[1];
    const float* v   = (const float*)d_in[2];
    const float* wq  = (const float*)d_in[3];
    const float* wk  = (const float*)d_in[4];
    const float* wv  = (const float*)d_in[5];
    const float* wo  = (const float*)d_in[6];
    const float* wob = (const float*)d_in[7];

    float* QP = (float*)d_ws;
    float* KP = QP + (size_t)8192 * 1024;
    unsigned short* VT = (unsigned short*)(KP + (size_t)8192 * 1024);
    unsigned short* AO = VT + (size_t)8192 * 1024;

    // weight scratch inside d_out (final gemm overwrites all of d_out)
    unsigned short* scr = (unsigned short*)d_out;
    const int M1 = 1 << 20;
    const short* wqh = (const short*)(scr);
    const short* wql = (const short*)(scr + M1);
    const short* wkh = (const short*)(scr + 2 * M1);
    const short* wkl = (const short*)(scr + 3 * M1);
    const void*  wv16 = (const void*)(scr + 4 * M1);

    prep_k<<<12288, 256, 0, stream>>>(wq, wk, wv, scr);
    gemm_qk2<<<256, 512, 0, stream>>>(q, wqh, wql, QP, k, wkh, wkl, KP);
    rope_pack<<<4096, 256, 0, stream>>>(QP, KP);
    gemm16<0, 1, 0><<<dim3(8, 64), 256, 0, stream>>>(v, wv16, (void*)VT, nullptr);
    attn_k<<<dim3(64, 16, 2), 256, 0, stream>>>((const unsigned short*)QP,
                                                (const unsigned short*)KP, VT, AO);
    gemm16<1, 0, 1><<<dim3(8, 64), 256, 0, stream>>>(AO, wo, d_out, wob);
}

// Round 2
// 419.100 us; speedup vs baseline: 1.0907x; 1.0254x over previous
//
#include <hip/hip_runtime.h>

// ---------------------------------------------------------------------------
// SlidingWindowAttention — fp32 in/out.
// Logit path: bf16 hi/lo 3-term MFMA. Split uses INTEGER RNE (immune to
// fp-contraction). Value path: fp16 (V-proj, P, V, AO, out-proj).
//
// gemm_qk2: 256x256 tile, BK=32, 512 thr (8 waves 2m x 4n), dbuf LDS 128KB.
// 2 barriers/K-step: head {STAGE_B(t+1); vmcnt(8)=B(t) landed; barrier},
// then PH1(ah*bh) -> PH2(ah*bl) -> [vmcnt(4); A-split -> slot^1; issue
// A(t+2)] -> PH3(al*bh) -> lgkm(0); barrier. Split VALU sits between MFMA
// clusters (co-issues with other wave's MFMA); no vmcnt drains to 0 in loop.
// XOR bank-swizzle on A/B tiles, setprio around MFMA clusters, XCD-chunked
// block swizzle.
//
// ws (96 MB): QP[0,32) fp32->packed hi/lo | KP[32,64) | VT fp16 [64,80) |
//             AO fp16 [80,96)
// d_out used as scratch for pre-split weights (first 10 MB), overwritten by
// the final out-projection (sole writer of d_out).
// ---------------------------------------------------------------------------

typedef __attribute__((ext_vector_type(8))) short short8v;
typedef __attribute__((ext_vector_type(4))) float float4v;
typedef __attribute__((ext_vector_type(8))) _Float16 half8v;

#define MFMA_BF16(A_, B_, C_) __builtin_amdgcn_mfma_f32_16x16x32_bf16((A_), (B_), (C_), 0, 0, 0)
#define MFMA_F16(A_, B_, C_)  __builtin_amdgcn_mfma_f32_16x16x32_f16((A_), (B_), (C_), 0, 0, 0)

#define VMW_(n) asm volatile("s_waitcnt vmcnt(" #n ")" ::: "memory")
#define VMW(n) VMW_(n)
#define LGKM0 asm volatile("s_waitcnt lgkmcnt(0)" ::: "memory")
#define BARF do { __builtin_amdgcn_s_barrier(); asm volatile("" ::: "memory"); } while (0)
#define FENCE asm volatile("" ::: "memory")

// hi = RNE(x -> bf16) via INTEGER rounding (cannot be contracted/fused);
// lo = x - hi exact in fp32; packed by truncation (err <= 2^-17 |x|).
__device__ __forceinline__ void split_rn(float x, short& h, short& l) {
    unsigned int u = __float_as_uint(x);
    u += 0x7fffu + ((u >> 16) & 1u);          // RNE in integer domain
    unsigned int hb = u & 0xffff0000u;
    h = (short)(hb >> 16);
    float lo = x - __uint_as_float(hb);       // exact (Sterbenz-ish, hi near x)
    l = (short)(__float_as_uint(lo) >> 16);   // truncate lo to bf16
}

// async 16B global -> LDS (wave-uniform LDS base + lane*16)
__device__ __forceinline__ void dma16(const void* g, void* l) {
    __builtin_amdgcn_global_load_lds(
        (__attribute__((address_space(1))) void*)g,
        (__attribute__((address_space(3))) void*)l, 16, 0, 0);
}

// ---------------- prep: weight splits/cvts into d_out scratch ----------------
// scr ushort layout: [0,1M)=wqh [1M,2M)=wql [2M,3M)=wkh [3M,4M)=wkl [4M,5M)=wv16
__global__ __launch_bounds__(256) void prep_k(
    const float* __restrict__ wq, const float* __restrict__ wk,
    const float* __restrict__ wv, unsigned short* __restrict__ scr)
{
    const int M1 = 1 << 20;
    unsigned int tid = blockIdx.x * 256 + threadIdx.x;   // 0 .. 3M-1
    if (tid < (unsigned)M1) {
        short h, l; split_rn(wq[tid], h, l);
        scr[tid] = (unsigned short)h;
        scr[M1 + tid] = (unsigned short)l;
    } else if (tid < (unsigned)(2 * M1)) {
        unsigned int i = tid - M1;
        short h, l; split_rn(wk[i], h, l);
        scr[2 * M1 + i] = (unsigned short)h;
        scr[3 * M1 + i] = (unsigned short)l;
    } else {
        unsigned int i = tid - 2 * M1;
        scr[4 * M1 + i] = __builtin_bit_cast(unsigned short, (_Float16)wv[i]);
    }
}

// ---------------- Q/K projection: C = A * B^T, 3-term bf16 hi/lo ----------------
// 256x256 tile, BK=32, 2-barrier staggered counted-vmcnt schedule (see header).
__global__ __launch_bounds__(512, 2) void gemm_qk2(
    const float* __restrict__ A0, const short* __restrict__ Bh0,
    const short* __restrict__ Bl0, float* __restrict__ C0,
    const float* __restrict__ A1, const short* __restrict__ Bh1,
    const short* __restrict__ Bl1, float* __restrict__ C1)
{
    // LDS: slot p at p*32768 shorts. Within slot (shorts):
    //   Ah +0, Al +8192, Bh +16384, Bl +24576; each array 256 rows x 32 cols.
    __shared__ __align__(16) short S[2 * 32768];   // 128 KiB

    // XCD-chunked swizzle: consecutive cid share an XCD; cid -> (z, m, n) with
    // the 4 n-blocks of one A-stripe adjacent (L2 A-reuse within XCD).
    const int bid = blockIdx.x;                 // grid = 256 exactly
    const int cid = ((bid & 7) << 5) | (bid >> 3);
    const int z   = cid >> 7;
    const int rem = cid & 127;
    const int bm  = (rem >> 2) << 8;            // 32 m-blocks * 256
    const int bn  = (rem & 3) << 8;             // 4 n-blocks * 256

    const float* Ap  = z ? A1  : A0;
    const short* Bhp = z ? Bh1 : Bh0;
    const short* Blp = z ? Bl1 : Bl0;
    float*       Cp  = z ? C1  : C0;

    const int t = threadIdx.x;
    const int wave = t >> 6, lane = t & 63;
    const int c16 = lane & 15, quad = lane >> 4;
    const int wm = (wave >> 2) << 7;            // 0 / 128
    const int wn = (wave & 3) << 6;             // 0 / 64 / 128 / 192

    // A staging: thread covers row ar, 16 cols (half-row) -> 2 swizzled 8-chunks
    const int ar = t >> 1;                      // 0..255
    const int ah16 = (t & 1) << 4;
    const int fA = (ar & 3) ^ ((ar >> 2) & 3);
    const int swA0 = ((((t & 1) << 1) | 0) ^ fA) << 3;   // shorts
    const int swA1 = ((((t & 1) << 1) | 1) ^ fA) << 3;

    // B dma: lane covers row (32*wave + 16*g + br), pre-swizzled source slot
    const int br  = lane >> 2;                  // 0..15
    const int fsl = (((lane & 3) ^ ((br & 3) ^ ((br >> 2) & 3))) << 3); // shorts

    // fragment read slot (swizzled): wanted slot = quad, row&15 = c16
    const int frd = ((quad ^ ((c16 & 3) ^ ((c16 >> 2) & 3))) << 3);     // shorts

    float4v acc[8][4];
#pragma unroll
    for (int i = 0; i < 8; i++)
#pragma unroll
        for (int j = 0; j < 4; j++) acc[i][j] = (float4v){0.f, 0.f, 0.f, 0.f};

#define STAGE_B(pp, kk)                                                          \
    do {                                                                         \
        const size_t rb = (size_t)(bn + (wave << 5) + br) * 1024 + (kk) + fsl;   \
        short* dh = S + (pp) * 32768 + 16384 + (wave << 10);                     \
        short* dl = dh + 8192;                                                   \
        dma16(Bhp + rb,             dh);                                         \
        dma16(Bhp + rb + 16 * 1024, dh + 512);                                   \
        dma16(Blp + rb,             dl);                                         \
        dma16(Blp + rb + 16 * 1024, dl + 512);                                   \
    } while (0)

#define SPLIT_WRITE(sp_)                                                         \
    do {                                                                         \
        short8v h0, l0, h1, l1;                                                  \
        _Pragma("unroll")                                                        \
        for (int jj = 0; jj < 4; jj++) {                                         \
            short hh, ll;                                                        \
            split_rn(ap0[jj], hh, ll); h0[jj] = hh;     l0[jj] = ll;             \
            split_rn(ap1[jj], hh, ll); h0[jj + 4] = hh; l0[jj + 4] = ll;         \
            split_rn(ap2[jj], hh, ll); h1[jj] = hh;     l1[jj] = ll;             \
            split_rn(ap3[jj], hh, ll); h1[jj + 4] = hh; l1[jj + 4] = ll;         \
        }                                                                        \
        short* abase = (sp_) + ar * 32;                                          \
        *(short8v*)(abase + swA0) = h0;                                          \
        *(short8v*)(abase + swA1) = h1;                                          \
        *(short8v*)(abase + 8192 + swA0) = l0;                                   \
        *(short8v*)(abase + 8192 + swA1) = l1;                                   \
    } while (0)

#define MFMA_CLUSTER(AARR, BARR)                                                 \
    do {                                                                         \
        __builtin_amdgcn_s_setprio(1);                                           \
        _Pragma("unroll")                                                        \
        for (int i = 0; i < 8; i++)                                              \
            _Pragma("unroll")                                                    \
            for (int j = 0; j < 4; j++)                                          \
                acc[i][j] = MFMA_BF16(AARR[i & 7], BARR[j & 3], acc[i][j]);      \
        __builtin_amdgcn_s_setprio(0);                                           \
    } while (0)

    // prologue: A(0) regs first (oldest in vmcnt queue), then B(0) dma -> slot 0
    const float* arow = Ap + (size_t)(bm + ar) * 1024 + ah16;
    float4v ap0 = *(const float4v*)(arow + 0);
    float4v ap1 = *(const float4v*)(arow + 4);
    float4v ap2 = *(const float4v*)(arow + 8);
    float4v ap3 = *(const float4v*)(arow + 12);
    FENCE;                          // pin A(0) loads before B(0) dma in vmcnt queue
    STAGE_B(0, 0);
    VMW(4);                         // A(0) landed (B(0) in flight)
    SPLIT_WRITE(S);                 // -> slot 0 A region
    FENCE;
    ap0 = *(const float4v*)(arow + 32);   // issue A(1)
    ap1 = *(const float4v*)(arow + 36);
    ap2 = *(const float4v*)(arow + 40);
    ap3 = *(const float4v*)(arow + 44);
    LGKM0;                          // split writes done (visible after first barrier)

    // steady-state invariant entering iter tt: vmcnt queue = [B(tt):4, A(tt+1):4]
    int kb = 0;
#pragma unroll 1
    for (int tt = 0; tt < 31; ++tt, kb += 32) {
        short* sp = S + (tt & 1) * 32768;
        short* sn = S + ((tt & 1) ^ 1) * 32768;

        STAGE_B((tt & 1) ^ 1, kb + 32);   // B(tt+1) -> other slot (last read pre-barrier of prev iter)
        VMW(8);                           // B(tt) landed; A(tt+1)+B(tt+1) stay in flight
        BARF;                             // all waves' B(tt) + split A(tt) visible

        // PH1: hi*hi
        short8v ahv[8], bhv[4];
#pragma unroll
        for (int i = 0; i < 8; i++)
            ahv[i] = *(const short8v*)(sp + (wm + i * 16 + c16) * 32 + frd);
#pragma unroll
        for (int j = 0; j < 4; j++)
            bhv[j] = *(const short8v*)(sp + 16384 + (wn + j * 16 + c16) * 32 + frd);
        MFMA_CLUSTER(ahv, bhv);

        // PH2: Ah*Bl (ahv kept in regs; no barrier — Bl(tt) waited at head)
        {
            short8v blv[4];
#pragma unroll
            for (int j = 0; j < 4; j++)
                blv[j] = *(const short8v*)(sp + 24576 + (wn + j * 16 + c16) * 32 + frd);
            MFMA_CLUSTER(ahv, blv);
        }

        // A split for next tile, between MFMA clusters (overlaps matrix pipe)
        VMW(4);                           // A(tt+1) regs landed (B(tt+1) in flight)
        SPLIT_WRITE(sn);
        FENCE;
        {
            int kn = kb + 64;
            if (kn >= 1024) kn = 0;       // tt==30: clamp (junk load, never used)
            ap0 = *(const float4v*)(arow + kn);
            ap1 = *(const float4v*)(arow + kn + 4);
            ap2 = *(const float4v*)(arow + kn + 8);
            ap3 = *(const float4v*)(arow + kn + 12);
        }

        // PH3: Al*Bh (bhv kept in regs)
        {
            short8v alv[8];
#pragma unroll
            for (int i = 0; i < 8; i++)
                alv[i] = *(const short8v*)(sp + 8192 + (wm + i * 16 + c16) * 32 + frd);
            MFMA_CLUSTER(alv, bhv);
        }
        LGKM0;                            // split writes + reads of slot sp done
        BARF;
    }

    // peeled tile 31 (slot 1): queue = [B(31):4, A(32)-junk:4]
    {
        short* sp = S + 32768;
        VMW(4);                           // B(31) landed (junk A may remain)
        BARF;
        short8v ahv[8], bhv[4];
#pragma unroll
        for (int i = 0; i < 8; i++)
            ahv[i] = *(const short8v*)(sp + (wm + i * 16 + c16) * 32 + frd);
#pragma unroll
        for (int j = 0; j < 4; j++)
            bhv[j] = *(const short8v*)(sp + 16384 + (wn + j * 16 + c16) * 32 + frd);
        MFMA_CLUSTER(ahv, bhv);
        {
            short8v blv[4];
#pragma unroll
            for (int j = 0; j < 4; j++)
                blv[j] = *(const short8v*)(sp + 24576 + (wn + j * 16 + c16) * 32 + frd);
            MFMA_CLUSTER(ahv, blv);
        }
        {
            short8v alv[8];
#pragma unroll
            for (int i = 0; i < 8; i++)
                alv[i] = *(const short8v*)(sp + 8192 + (wm + i * 16 + c16) * 32 + frd);
            MFMA_CLUSTER(alv, bhv);
        }
    }

#undef STAGE_B
#undef SPLIT_WRITE
#undef MFMA_CLUSTER

    // epilogue: C/D 16x16: row = quad*4 + r, col = c16
#pragma unroll
    for (int i = 0; i < 8; i++) {
        const size_t gr0 = (size_t)(bm + wm + i * 16 + quad * 4);
#pragma unroll
        for (int j = 0; j < 4; j++) {
            const int gc = bn + wn + j * 16 + c16;
#pragma unroll
            for (int r = 0; r < 4; r++)
                Cp[(gr0 + r) * 1024 + gc] = acc[i][j][r];
        }
    }
}

// ---------------- fp16 GEMM (V-proj / out-proj), C = A * B^T ----------------
// AF16/BF16: operand already fp16 -> DMA staging; else fp32 + cvt.
// OMODE 0: store fp16 VT transposed. OMODE 1: fp32 + bias -> Cp.
template <int AF16, int BF16, int OMODE>
__global__ __launch_bounds__(256) void gemm16(
    const void* __restrict__ Ap, const void* __restrict__ Bp,
    void* __restrict__ Cp, const float* __restrict__ bias)
{
    const int N = 1024, K = 1024;

    __shared__ __align__(16) short As[128 * 32];
    __shared__ __align__(16) short Bs[128 * 32];

    const int t = threadIdx.x;
    const int bm = blockIdx.y << 7;
    const int bn = blockIdx.x << 7;
    const int lane = t & 63;
    const int wave = t >> 6;
    const int wm = (wave >> 1) << 6;
    const int wn = (wave & 1) << 6;
    const int c16 = lane & 15;
    const int quad = lane >> 4;
    const int lr = t >> 2;
    const int lc = (t & 3) << 3;

    float4v acc[4][4];
#pragma unroll
    for (int i = 0; i < 4; i++)
#pragma unroll
        for (int j = 0; j < 4; j++) acc[i][j] = (float4v){0.f, 0.f, 0.f, 0.f};

    for (int kb = 0; kb < K; kb += 32) {
        if (AF16) {
            const _Float16* Af = (const _Float16*)Ap;
#pragma unroll
            for (int g = 0; g < 2; g++)
                dma16(Af + (size_t)(bm + g * 64 + lr) * K + kb + lc,
                      As + g * 2048 + wave * 512);
        } else {
            const float* Af = (const float*)Ap;
#pragma unroll
            for (int g = 0; g < 2; g++) {
                const float* src = Af + (size_t)(bm + g * 64 + lr) * K + kb + lc;
                float4v f0 = *(const float4v*)src;
                float4v f1 = *(const float4v*)(src + 4);
                half8v h;
#pragma unroll
                for (int j = 0; j < 8; j++) h[j] = (_Float16)((j < 4) ? f0[j] : f1[j - 4]);
                *(half8v*)(As + (g * 64 + lr) * 32 + lc) = h;
            }
        }
        if (BF16) {
            const _Float16* Bf = (const _Float16*)Bp;
#pragma unroll
            for (int g = 0; g < 2; g++)
                dma16(Bf + (size_t)(bn + g * 64 + lr) * K + kb + lc,
                      Bs + g * 2048 + wave * 512);
        } else {
            const float* Bf = (const float*)Bp;
#pragma unroll
            for (int g = 0; g < 2; g++) {
                const float* src = Bf + (size_t)(bn + g * 64 + lr) * K + kb + lc;
                float4v f0 = *(const float4v*)src;
                float4v f1 = *(const float4v*)(src + 4);
                half8v h;
#pragma unroll
                for (int j = 0; j < 8; j++) h[j] = (_Float16)((j < 4) ? f0[j] : f1[j - 4]);
                *(half8v*)(Bs + (g * 64 + lr) * 32 + lc) = h;
            }
        }
        __syncthreads();

        half8v ah[4], bh[4];
#pragma unroll
        for (int i = 0; i < 4; i++)
            ah[i] = *(const half8v*)(As + (wm + i * 16 + c16) * 32 + quad * 8);
#pragma unroll
        for (int j = 0; j < 4; j++)
            bh[j] = *(const half8v*)(Bs + (wn + j * 16 + c16) * 32 + quad * 8);
#pragma unroll
        for (int i = 0; i < 4; i++)
#pragma unroll
            for (int j = 0; j < 4; j++)
                acc[i][j] = MFMA_F16(ah[i], bh[j], acc[i][j]);
        __syncthreads();
    }

#pragma unroll
    for (int i = 0; i < 4; i++)
#pragma unroll
        for (int j = 0; j < 4; j++)
#pragma unroll
            for (int r = 0; r < 4; r++) {
                int gr = bm + wm + i * 16 + quad * 4 + r;
                int gc = bn + wn + j * 16 + c16;
                float vv = acc[i][j][r];
                if (OMODE == 0) {
                    ((unsigned short*)Cp)[((size_t)(gc << 1) + (gr >> 12)) * 4096 + (gr & 4095)] =
                        __builtin_bit_cast(unsigned short, (_Float16)vv);
                } else {
                    ((float*)Cp)[(size_t)gr * N + gc] = vv + bias[gc];
                }
            }
}

// ---------------- RoPE + in-place hi/lo pack, 4 rows share sincos ----------------
__global__ __launch_bounds__(256) void rope_pack(float* __restrict__ QP, float* __restrict__ KP)
{
    int sp = blockIdx.x;            // 0..4095
    int t = threadIdx.x;
    float* rows[4] = { QP + ((size_t)sp << 10), QP + ((size_t)(4096 + sp) << 10),
                       KP + ((size_t)sp << 10), KP + ((size_t)(4096 + sp) << 10) };

    float c[2], sn[2];
    float x1[4][2], x2[4][2];
#pragma unroll
    for (int p = 0; p < 2; p++) {
        int j = t + p * 256;
        float freq = __expf(-0.017988946f * (float)j);   // 10000^(-j/512)
        float ang = (float)sp * freq;
        sincosf(ang, &sn[p], &c[p]);
#pragma unroll
        for (int r = 0; r < 4; r++) {
            x1[r][p] = rows[r][j];
            x2[r][p] = rows[r][j + 512];
        }
    }
    __syncthreads();
#pragma unroll
    for (int r = 0; r < 4; r++) {
        unsigned short* u = (unsigned short*)rows[r];
#pragma unroll
        for (int p = 0; p < 2; p++) {
            int j = t + p * 256;
            float y1 = x1[r][p] * c[p] - x2[r][p] * sn[p];
            float y2 = x1[r][p] * sn[p] + x2[r][p] * c[p];
            short h1, l1, h2, l2;
            split_rn(y1, h1, l1);
            split_rn(y2, h2, l2);
            u[j] = (unsigned short)h1;
            u[j + 512] = (unsigned short)h2;
            u[1024 + j] = (unsigned short)l1;
            u[1024 + j + 512] = (unsigned short)l2;
        }
    }
}

// ---------------- Banded attention ----------------
// QK^T: bf16 hi/lo 3-term from packed QP/KP. PV: fp16 (P scaled x512).
__global__ __launch_bounds__(256) void attn_k(
    const unsigned short* __restrict__ QHL, const unsigned short* __restrict__ KHL,
    const unsigned short* __restrict__ VT, unsigned short* __restrict__ AO)
{
    const int S = 4096;
    const float NEG = -1e30f;
    const float PSC = 512.0f;
    const int bq = blockIdx.x, h = blockIdx.y, b = blockIdx.z;
    const int t = threadIdx.x;
    const int wave = t >> 6, lane = t & 63;
    const int col = lane & 15, quad = lane >> 4;
    const int qg = (bq << 6) + (wave << 4);

    __shared__ __align__(16) short Khs[64 * 72];
    __shared__ __align__(16) short Kls[64 * 72];
    __shared__ __align__(16) short Vs[64 * 72];
    __shared__ __align__(16) short Ps[4][16 * 72];
    short* myP = &Ps[wave][0];

    const int sk = t >> 3;        // 0..31
    const int sd = (t & 7) << 3;  // 0..56 step 8

    short8v qh[2], ql[2];
    {
        const unsigned short* qr = QHL + ((size_t)(b * S + qg + col) << 11) + h * 64 + quad * 8;
        qh[0] = *(const short8v*)(qr);
        qh[1] = *(const short8v*)(qr + 32);
        ql[0] = *(const short8v*)(qr + 1024);
        ql[1] = *(const short8v*)(qr + 1024 + 32);
    }

    float mrun[4], lrun[4];
    float4v O[4];
#pragma unroll
    for (int r = 0; r < 4; r++) { mrun[r] = NEG; lrun[r] = 0.f; }
#pragma unroll
    for (int t4 = 0; t4 < 4; t4++) O[t4] = (float4v){0.f, 0.f, 0.f, 0.f};

    const int blk0 = bq << 6;
    const int kstart = (blk0 - 256 > 0) ? (blk0 - 256) : 0;
    const int kend = (blk0 + 320 < S) ? (blk0 + 320) : S;

    for (int kb = kstart; kb < kend; kb += 64) {
#pragma unroll
        for (int p = 0; p < 2; p++) {
            int key = p * 32 + sk;
            const unsigned short* krow = KHL + ((size_t)(b * S + kb + key) << 11) + h * 64 + sd;
            *(short8v*)(Khs + key * 72 + sd) = *(const short8v*)krow;
            *(short8v*)(Kls + key * 72 + sd) = *(const short8v*)(krow + 1024);
            int dm = p * 32 + sk;
            const unsigned short* vrow = VT + ((size_t)((h * 64 + dm) << 1) + b) * S + kb + sd;
            *(short8v*)(Vs + dm * 72 + sd) = *(const short8v*)vrow;
        }
        __syncthreads();

        float4v sv[4];
#pragma unroll
        for (int c = 0; c < 4; c++) {
            const short* kro = Khs + (c * 16 + col) * 72 + quad * 8;
            const short* klo = Kls + (c * 16 + col) * 72 + quad * 8;
            short8v kh0 = *(const short8v*)kro;
            short8v kh1 = *(const short8v*)(kro + 32);
            short8v kl0 = *(const short8v*)klo;
            short8v kl1 = *(const short8v*)(klo + 32);
            float4v sc = (float4v){0.f, 0.f, 0.f, 0.f};
            sc = MFMA_BF16(qh[0], kh0, sc);
            sc = MFMA_BF16(qh[1], kh1, sc);
            sc = MFMA_BF16(qh[0], kl0, sc);
            sc = MFMA_BF16(qh[1], kl1, sc);
            sc = MFMA_BF16(ql[0], kh0, sc);
            sc = MFMA_BF16(ql[1], kh1, sc);
            sv[c] = sc;
        }

        float mx[4], alpha[4], psum[4];
#pragma unroll
        for (int r = 0; r < 4; r++) {
            int qrow = qg + quad * 4 + r;
            float m = NEG;
#pragma unroll
            for (int c = 0; c < 4; c++) {
                int key = kb + c * 16 + col;
                float vv = (key >= qrow - 256 && key <= qrow + 256) ? sv[c][r] * 8.0f : NEG;
                sv[c][r] = vv;
                m = fmaxf(m, vv);
            }
            mx[r] = m;
        }
#pragma unroll
        for (int st = 1; st < 16; st <<= 1)
#pragma unroll
            for (int r = 0; r < 4; r++) mx[r] = fmaxf(mx[r], __shfl_xor(mx[r], st, 64));

#pragma unroll
        for (int r = 0; r < 4; r++) {
            float mn = fmaxf(mrun[r], mx[r]);
            alpha[r] = __expf(mrun[r] - mn);
            mrun[r] = mn;
            float ps = 0.f;
#pragma unroll
            for (int c = 0; c < 4; c++) {
                float p = __expf(sv[c][r] - mn);
                ps += p;
                myP[(quad * 4 + r) * 72 + c * 16 + col] =
                    __builtin_bit_cast(short, (_Float16)(p * PSC));
            }
            psum[r] = ps;
        }
#pragma unroll
        for (int st = 1; st < 16; st <<= 1)
#pragma unroll
            for (int r = 0; r < 4; r++) psum[r] += __shfl_xor(psum[r], st, 64);
#pragma unroll
        for (int r = 0; r < 4; r++) lrun[r] = lrun[r] * alpha[r] + psum[r];
#pragma unroll
        for (int t4 = 0; t4 < 4; t4++)
#pragma unroll
            for (int r = 0; r < 4; r++) O[t4][r] *= alpha[r];

#pragma unroll
        for (int kf = 0; kf < 2; kf++) {
            half8v pa = *(const half8v*)(myP + col * 72 + kf * 32 + quad * 8);
#pragma unroll
            for (int t4 = 0; t4 < 4; t4++) {
                half8v vb = *(const half8v*)(Vs + (t4 * 16 + col) * 72 + kf * 32 + quad * 8);
                O[t4] = MFMA_F16(pa, vb, O[t4]);
            }
        }
        __syncthreads();
    }

#pragma unroll
    for (int r = 0; r < 4; r++) {
        float inv = (lrun[r] > 0.f) ? (1.0f / (lrun[r] * PSC)) : 0.f;
        unsigned short* orow = AO + (size_t)(b * S + qg + quad * 4 + r) * 1024 + h * 64;
#pragma unroll
        for (int t4 = 0; t4 < 4; t4++)
            orow[t4 * 16 + col] = __builtin_bit_cast(unsigned short, (_Float16)(O[t4][r] * inv));
    }
}

extern "C" void kernel_launch(void* const* d_in, const int* in_sizes, int n_in,
                              void* d_out, int out_size, void* d_ws, size_t ws_size,
                              hipStream_t stream) {
    const float* q   = (const float*)d_in[0];
    const float* k   = (const float*)d_in[1];
    const float* v   = (const float*)d_in[2];
    const float* wq  = (const float*)d_in[3];
    const float* wk  = (const float*)d_in[4];
    const float* wv  = (const float*)d_in[5];
    const float* wo  = (const float*)d_in[6];
    const float* wob = (const float*)d_in[7];

    float* QP = (float*)d_ws;
    float* KP = QP + (size_t)8192 * 1024;
    unsigned short* VT = (unsigned short*)(KP + (size_t)8192 * 1024);
    unsigned short* AO = VT + (size_t)8192 * 1024;

    // weight scratch inside d_out (final gemm overwrites all of d_out)
    unsigned short* scr = (unsigned short*)d_out;
    const int M1 = 1 << 20;
    const short* wqh = (const short*)(scr);
    const short* wql = (const short*)(scr + M1);
    const short* wkh = (const short*)(scr + 2 * M1);
    const short* wkl = (const short*)(scr + 3 * M1);
    const void*  wv16 = (const void*)(scr + 4 * M1);

    prep_k<<<12288, 256, 0, stream>>>(wq, wk, wv, scr);
    gemm_qk2<<<256, 512, 0, stream>>>(q, wqh, wql, QP, k, wkh, wkl, KP);
    rope_pack<<<4096, 256, 0, stream>>>(QP, KP);
    gemm16<0, 1, 0><<<dim3(8, 64), 256, 0, stream>>>(v, wv16, (void*)VT, nullptr);
    attn_k<<<dim3(64, 16, 2), 256, 0, stream>>>((const unsigned short*)QP,
                                                (const unsigned short*)KP, VT, AO);
    gemm16<1, 0, 1><<<dim3(8, 64), 256, 0, stream>>>(AO, wo, d_out, wob);
}

// Round 3
// 411.823 us; speedup vs baseline: 1.1100x; 1.0177x over previous
//
#include <hip/hip_runtime.h>

// ---------------------------------------------------------------------------
// SlidingWindowAttention — fp32 in/out.
// Logit path: bf16 hi/lo 3-term MFMA. Split uses INTEGER RNE (immune to
// fp-contraction). Value path: fp16 (V-proj, P, V, AO, out-proj).
//
// gemm_qk2: 256x256 tile, BK=32, 2-barrier counted-vmcnt schedule (R2).
// attn_k (R3): QBLK=128, 8 waves/block, global_load_lds K/V staging with
// source-XOR swizzle (chunk ^= row&7), double-buffered LDS + vmcnt(3),
// interior-tile mask hoist, sqrt(dk)=8 folded into Q at rope_pack (exact),
// defer-rescale online softmax, setprio around MFMA clusters.
//
// ws (96 MB): QP[0,32) fp32->packed hi/lo | KP[32,64) | VT fp16 [64,80) |
//             AO fp16 [80,96)
// d_out used as scratch for pre-split weights (first 10 MB), overwritten by
// the final out-projection (sole writer of d_out).
// ---------------------------------------------------------------------------

typedef __attribute__((ext_vector_type(8))) short short8v;
typedef __attribute__((ext_vector_type(4))) float float4v;
typedef __attribute__((ext_vector_type(8))) _Float16 half8v;

#define MFMA_BF16(A_, B_, C_) __builtin_amdgcn_mfma_f32_16x16x32_bf16((A_), (B_), (C_), 0, 0, 0)
#define MFMA_F16(A_, B_, C_)  __builtin_amdgcn_mfma_f32_16x16x32_f16((A_), (B_), (C_), 0, 0, 0)

#define VMW_(n) asm volatile("s_waitcnt vmcnt(" #n ")" ::: "memory")
#define VMW(n) VMW_(n)
#define LGKM0 asm volatile("s_waitcnt lgkmcnt(0)" ::: "memory")
#define BARF do { __builtin_amdgcn_s_barrier(); asm volatile("" ::: "memory"); } while (0)
#define FENCE asm volatile("" ::: "memory")

// hi = RNE(x -> bf16) via INTEGER rounding (cannot be contracted/fused);
// lo = x - hi exact in fp32; packed by truncation (err <= 2^-17 |x|).
__device__ __forceinline__ void split_rn(float x, short& h, short& l) {
    unsigned int u = __float_as_uint(x);
    u += 0x7fffu + ((u >> 16) & 1u);          // RNE in integer domain
    unsigned int hb = u & 0xffff0000u;
    h = (short)(hb >> 16);
    float lo = x - __uint_as_float(hb);       // exact (Sterbenz-ish, hi near x)
    l = (short)(__float_as_uint(lo) >> 16);   // truncate lo to bf16
}

// async 16B global -> LDS (wave-uniform LDS base + lane*16)
__device__ __forceinline__ void dma16(const void* g, void* l) {
    __builtin_amdgcn_global_load_lds(
        (__attribute__((address_space(1))) void*)g,
        (__attribute__((address_space(3))) void*)l, 16, 0, 0);
}

// ---------------- prep: weight splits/cvts into d_out scratch ----------------
// scr ushort layout: [0,1M)=wqh [1M,2M)=wql [2M,3M)=wkh [3M,4M)=wkl [4M,5M)=wv16
__global__ __launch_bounds__(256) void prep_k(
    const float* __restrict__ wq, const float* __restrict__ wk,
    const float* __restrict__ wv, unsigned short* __restrict__ scr)
{
    const int M1 = 1 << 20;
    unsigned int tid = blockIdx.x * 256 + threadIdx.x;   // 0 .. 3M-1
    if (tid < (unsigned)M1) {
        short h, l; split_rn(wq[tid], h, l);
        scr[tid] = (unsigned short)h;
        scr[M1 + tid] = (unsigned short)l;
    } else if (tid < (unsigned)(2 * M1)) {
        unsigned int i = tid - M1;
        short h, l; split_rn(wk[i], h, l);
        scr[2 * M1 + i] = (unsigned short)h;
        scr[3 * M1 + i] = (unsigned short)l;
    } else {
        unsigned int i = tid - 2 * M1;
        scr[4 * M1 + i] = __builtin_bit_cast(unsigned short, (_Float16)wv[i]);
    }
}

// ---------------- Q/K projection: C = A * B^T, 3-term bf16 hi/lo ----------------
// 256x256 tile, BK=32, 2-barrier staggered counted-vmcnt schedule.
__global__ __launch_bounds__(512, 2) void gemm_qk2(
    const float* __restrict__ A0, const short* __restrict__ Bh0,
    const short* __restrict__ Bl0, float* __restrict__ C0,
    const float* __restrict__ A1, const short* __restrict__ Bh1,
    const short* __restrict__ Bl1, float* __restrict__ C1)
{
    // LDS: slot p at p*32768 shorts. Within slot (shorts):
    //   Ah +0, Al +8192, Bh +16384, Bl +24576; each array 256 rows x 32 cols.
    __shared__ __align__(16) short S[2 * 32768];   // 128 KiB

    const int bid = blockIdx.x;                 // grid = 256 exactly
    const int cid = ((bid & 7) << 5) | (bid >> 3);
    const int z   = cid >> 7;
    const int rem = cid & 127;
    const int bm  = (rem >> 2) << 8;            // 32 m-blocks * 256
    const int bn  = (rem & 3) << 8;             // 4 n-blocks * 256

    const float* Ap  = z ? A1  : A0;
    const short* Bhp = z ? Bh1 : Bh0;
    const short* Blp = z ? Bl1 : Bl0;
    float*       Cp  = z ? C1  : C0;

    const int t = threadIdx.x;
    const int wave = t >> 6, lane = t & 63;
    const int c16 = lane & 15, quad = lane >> 4;
    const int wm = (wave >> 2) << 7;            // 0 / 128
    const int wn = (wave & 3) << 6;             // 0 / 64 / 128 / 192

    const int ar = t >> 1;                      // 0..255
    const int ah16 = (t & 1) << 4;
    const int fA = (ar & 3) ^ ((ar >> 2) & 3);
    const int swA0 = ((((t & 1) << 1) | 0) ^ fA) << 3;   // shorts
    const int swA1 = ((((t & 1) << 1) | 1) ^ fA) << 3;

    const int br  = lane >> 2;                  // 0..15
    const int fsl = (((lane & 3) ^ ((br & 3) ^ ((br >> 2) & 3))) << 3); // shorts

    const int frd = ((quad ^ ((c16 & 3) ^ ((c16 >> 2) & 3))) << 3);     // shorts

    float4v acc[8][4];
#pragma unroll
    for (int i = 0; i < 8; i++)
#pragma unroll
        for (int j = 0; j < 4; j++) acc[i][j] = (float4v){0.f, 0.f, 0.f, 0.f};

#define STAGE_B(pp, kk)                                                          \
    do {                                                                         \
        const size_t rb = (size_t)(bn + (wave << 5) + br) * 1024 + (kk) + fsl;   \
        short* dh = S + (pp) * 32768 + 16384 + (wave << 10);                     \
        short* dl = dh + 8192;                                                   \
        dma16(Bhp + rb,             dh);                                         \
        dma16(Bhp + rb + 16 * 1024, dh + 512);                                   \
        dma16(Blp + rb,             dl);                                         \
        dma16(Blp + rb + 16 * 1024, dl + 512);                                   \
    } while (0)

#define SPLIT_WRITE(sp_)                                                         \
    do {                                                                         \
        short8v h0, l0, h1, l1;                                                  \
        _Pragma("unroll")                                                        \
        for (int jj = 0; jj < 4; jj++) {                                         \
            short hh, ll;                                                        \
            split_rn(ap0[jj], hh, ll); h0[jj] = hh;     l0[jj] = ll;             \
            split_rn(ap1[jj], hh, ll); h0[jj + 4] = hh; l0[jj + 4] = ll;         \
            split_rn(ap2[jj], hh, ll); h1[jj] = hh;     l1[jj] = ll;             \
            split_rn(ap3[jj], hh, ll); h1[jj + 4] = hh; l1[jj + 4] = ll;         \
        }                                                                        \
        short* abase = (sp_) + ar * 32;                                          \
        *(short8v*)(abase + swA0) = h0;                                          \
        *(short8v*)(abase + swA1) = h1;                                          \
        *(short8v*)(abase + 8192 + swA0) = l0;                                   \
        *(short8v*)(abase + 8192 + swA1) = l1;                                   \
    } while (0)

#define MFMA_CLUSTER(AARR, BARR)                                                 \
    do {                                                                         \
        __builtin_amdgcn_s_setprio(1);                                           \
        _Pragma("unroll")                                                        \
        for (int i = 0; i < 8; i++)                                              \
            _Pragma("unroll")                                                    \
            for (int j = 0; j < 4; j++)                                          \
                acc[i][j] = MFMA_BF16(AARR[i & 7], BARR[j & 3], acc[i][j]);      \
        __builtin_amdgcn_s_setprio(0);                                           \
    } while (0)

    // prologue: A(0) regs first (oldest in vmcnt queue), then B(0) dma -> slot 0
    const float* arow = Ap + (size_t)(bm + ar) * 1024 + ah16;
    float4v ap0 = *(const float4v*)(arow + 0);
    float4v ap1 = *(const float4v*)(arow + 4);
    float4v ap2 = *(const float4v*)(arow + 8);
    float4v ap3 = *(const float4v*)(arow + 12);
    FENCE;                          // pin A(0) loads before B(0) dma in vmcnt queue
    STAGE_B(0, 0);
    VMW(4);                         // A(0) landed (B(0) in flight)
    SPLIT_WRITE(S);                 // -> slot 0 A region
    FENCE;
    ap0 = *(const float4v*)(arow + 32);   // issue A(1)
    ap1 = *(const float4v*)(arow + 36);
    ap2 = *(const float4v*)(arow + 40);
    ap3 = *(const float4v*)(arow + 44);
    LGKM0;                          // split writes done (visible after first barrier)

    // steady-state invariant entering iter tt: vmcnt queue = [B(tt):4, A(tt+1):4]
    int kb = 0;
#pragma unroll 1
    for (int tt = 0; tt < 31; ++tt, kb += 32) {
        short* sp = S + (tt & 1) * 32768;
        short* sn = S + ((tt & 1) ^ 1) * 32768;

        STAGE_B((tt & 1) ^ 1, kb + 32);   // B(tt+1) -> other slot
        VMW(8);                           // B(tt) landed; A(tt+1)+B(tt+1) stay in flight
        BARF;                             // all waves' B(tt) + split A(tt) visible

        // PH1: hi*hi
        short8v ahv[8], bhv[4];
#pragma unroll
        for (int i = 0; i < 8; i++)
            ahv[i] = *(const short8v*)(sp + (wm + i * 16 + c16) * 32 + frd);
#pragma unroll
        for (int j = 0; j < 4; j++)
            bhv[j] = *(const short8v*)(sp + 16384 + (wn + j * 16 + c16) * 32 + frd);
        MFMA_CLUSTER(ahv, bhv);

        // PH2: Ah*Bl (ahv kept in regs; no barrier — Bl(tt) waited at head)
        {
            short8v blv[4];
#pragma unroll
            for (int j = 0; j < 4; j++)
                blv[j] = *(const short8v*)(sp + 24576 + (wn + j * 16 + c16) * 32 + frd);
            MFMA_CLUSTER(ahv, blv);
        }

        // A split for next tile, between MFMA clusters (overlaps matrix pipe)
        VMW(4);                           // A(tt+1) regs landed (B(tt+1) in flight)
        SPLIT_WRITE(sn);
        FENCE;
        {
            int kn = kb + 64;
            if (kn >= 1024) kn = 0;       // tt==30: clamp (junk load, never used)
            ap0 = *(const float4v*)(arow + kn);
            ap1 = *(const float4v*)(arow + kn + 4);
            ap2 = *(const float4v*)(arow + kn + 8);
            ap3 = *(const float4v*)(arow + kn + 12);
        }

        // PH3: Al*Bh (bhv kept in regs)
        {
            short8v alv[8];
#pragma unroll
            for (int i = 0; i < 8; i++)
                alv[i] = *(const short8v*)(sp + 8192 + (wm + i * 16 + c16) * 32 + frd);
            MFMA_CLUSTER(alv, bhv);
        }
        LGKM0;                            // split writes + reads of slot sp done
        BARF;
    }

    // peeled tile 31 (slot 1): queue = [B(31):4, A(32)-junk:4]
    {
        short* sp = S + 32768;
        VMW(4);                           // B(31) landed (junk A may remain)
        BARF;
        short8v ahv[8], bhv[4];
#pragma unroll
        for (int i = 0; i < 8; i++)
            ahv[i] = *(const short8v*)(sp + (wm + i * 16 + c16) * 32 + frd);
#pragma unroll
        for (int j = 0; j < 4; j++)
            bhv[j] = *(const short8v*)(sp + 16384 + (wn + j * 16 + c16) * 32 + frd);
        MFMA_CLUSTER(ahv, bhv);
        {
            short8v blv[4];
#pragma unroll
            for (int j = 0; j < 4; j++)
                blv[j] = *(const short8v*)(sp + 24576 + (wn + j * 16 + c16) * 32 + frd);
            MFMA_CLUSTER(ahv, blv);
        }
        {
            short8v alv[8];
#pragma unroll
            for (int i = 0; i < 8; i++)
                alv[i] = *(const short8v*)(sp + 8192 + (wm + i * 16 + c16) * 32 + frd);
            MFMA_CLUSTER(alv, bhv);
        }
    }

#undef STAGE_B
#undef SPLIT_WRITE
#undef MFMA_CLUSTER

    // epilogue: C/D 16x16: row = quad*4 + r, col = c16
#pragma unroll
    for (int i = 0; i < 8; i++) {
        const size_t gr0 = (size_t)(bm + wm + i * 16 + quad * 4);
#pragma unroll
        for (int j = 0; j < 4; j++) {
            const int gc = bn + wn + j * 16 + c16;
#pragma unroll
            for (int r = 0; r < 4; r++)
                Cp[(gr0 + r) * 1024 + gc] = acc[i][j][r];
        }
    }
}

// ---------------- fp16 GEMM (V-proj / out-proj), C = A * B^T ----------------
template <int AF16, int BF16, int OMODE>
__global__ __launch_bounds__(256) void gemm16(
    const void* __restrict__ Ap, const void* __restrict__ Bp,
    void* __restrict__ Cp, const float* __restrict__ bias)
{
    const int N = 1024, K = 1024;

    __shared__ __align__(16) short As[128 * 32];
    __shared__ __align__(16) short Bs[128 * 32];

    const int t = threadIdx.x;
    const int bm = blockIdx.y << 7;
    const int bn = blockIdx.x << 7;
    const int lane = t & 63;
    const int wave = t >> 6;
    const int wm = (wave >> 1) << 6;
    const int wn = (wave & 1) << 6;
    const int c16 = lane & 15;
    const int quad = lane >> 4;
    const int lr = t >> 2;
    const int lc = (t & 3) << 3;

    float4v acc[4][4];
#pragma unroll
    for (int i = 0; i < 4; i++)
#pragma unroll
        for (int j = 0; j < 4; j++) acc[i][j] = (float4v){0.f, 0.f, 0.f, 0.f};

    for (int kb = 0; kb < K; kb += 32) {
        if (AF16) {
            const _Float16* Af = (const _Float16*)Ap;
#pragma unroll
            for (int g = 0; g < 2; g++)
                dma16(Af + (size_t)(bm + g * 64 + lr) * K + kb + lc,
                      As + g * 2048 + wave * 512);
        } else {
            const float* Af = (const float*)Ap;
#pragma unroll
            for (int g = 0; g < 2; g++) {
                const float* src = Af + (size_t)(bm + g * 64 + lr) * K + kb + lc;
                float4v f0 = *(const float4v*)src;
                float4v f1 = *(const float4v*)(src + 4);
                half8v h;
#pragma unroll
                for (int j = 0; j < 8; j++) h[j] = (_Float16)((j < 4) ? f0[j] : f1[j - 4]);
                *(half8v*)(As + (g * 64 + lr) * 32 + lc) = h;
            }
        }
        if (BF16) {
            const _Float16* Bf = (const _Float16*)Bp;
#pragma unroll
            for (int g = 0; g < 2; g++)
                dma16(Bf + (size_t)(bn + g * 64 + lr) * K + kb + lc,
                      Bs + g * 2048 + wave * 512);
        } else {
            const float* Bf = (const float*)Bp;
#pragma unroll
            for (int g = 0; g < 2; g++) {
                const float* src = Bf + (size_t)(bn + g * 64 + lr) * K + kb + lc;
                float4v f0 = *(const float4v*)src;
                float4v f1 = *(const float4v*)(src + 4);
                half8v h;
#pragma unroll
                for (int j = 0; j < 8; j++) h[j] = (_Float16)((j < 4) ? f0[j] : f1[j - 4]);
                *(half8v*)(Bs + (g * 64 + lr) * 32 + lc) = h;
            }
        }
        __syncthreads();

        half8v ah[4], bh[4];
#pragma unroll
        for (int i = 0; i < 4; i++)
            ah[i] = *(const half8v*)(As + (wm + i * 16 + c16) * 32 + quad * 8);
#pragma unroll
        for (int j = 0; j < 4; j++)
            bh[j] = *(const half8v*)(Bs + (wn + j * 16 + c16) * 32 + quad * 8);
#pragma unroll
        for (int i = 0; i < 4; i++)
#pragma unroll
            for (int j = 0; j < 4; j++)
                acc[i][j] = MFMA_F16(ah[i], bh[j], acc[i][j]);
        __syncthreads();
    }

#pragma unroll
    for (int i = 0; i < 4; i++)
#pragma unroll
        for (int j = 0; j < 4; j++)
#pragma unroll
            for (int r = 0; r < 4; r++) {
                int gr = bm + wm + i * 16 + quad * 4 + r;
                int gc = bn + wn + j * 16 + c16;
                float vv = acc[i][j][r];
                if (OMODE == 0) {
                    ((unsigned short*)Cp)[((size_t)(gc << 1) + (gr >> 12)) * 4096 + (gr & 4095)] =
                        __builtin_bit_cast(unsigned short, (_Float16)vv);
                } else {
                    ((float*)Cp)[(size_t)gr * N + gc] = vv + bias[gc];
                }
            }
}

// ---------------- RoPE + in-place hi/lo pack, 4 rows share sincos ----------------
// Q rows (r<2) additionally scaled by 8 = sqrt(dk) — exact (exponent shift),
// so attn_k consumes pre-scaled scores with zero per-tile VALU cost.
__global__ __launch_bounds__(256) void rope_pack(float* __restrict__ QP, float* __restrict__ KP)
{
    int sp = blockIdx.x;            // 0..4095
    int t = threadIdx.x;
    float* rows[4] = { QP + ((size_t)sp << 10), QP + ((size_t)(4096 + sp) << 10),
                       KP + ((size_t)sp << 10), KP + ((size_t)(4096 + sp) << 10) };

    float c[2], sn[2];
    float x1[4][2], x2[4][2];
#pragma unroll
    for (int p = 0; p < 2; p++) {
        int j = t + p * 256;
        float freq = __expf(-0.017988946f * (float)j);   // 10000^(-j/512)
        float ang = (float)sp * freq;
        sincosf(ang, &sn[p], &c[p]);
#pragma unroll
        for (int r = 0; r < 4; r++) {
            x1[r][p] = rows[r][j];
            x2[r][p] = rows[r][j + 512];
        }
    }
    __syncthreads();
#pragma unroll
    for (int r = 0; r < 4; r++) {
        unsigned short* u = (unsigned short*)rows[r];
        const float sc8 = (r < 2) ? 8.0f : 1.0f;   // fold sqrt(dk) into Q (exact)
#pragma unroll
        for (int p = 0; p < 2; p++) {
            int j = t + p * 256;
            float y1 = (x1[r][p] * c[p] - x2[r][p] * sn[p]) * sc8;
            float y2 = (x1[r][p] * sn[p] + x2[r][p] * c[p]) * sc8;
            short h1, l1, h2, l2;
            split_rn(y1, h1, l1);
            split_rn(y2, h2, l2);
            u[j] = (unsigned short)h1;
            u[j + 512] = (unsigned short)h2;
            u[1024 + j] = (unsigned short)l1;
            u[1024 + j + 512] = (unsigned short)l2;
        }
    }
}

// ---------------- Banded attention (R3) ----------------
// QBLK=128, 8 waves x 16 q-rows. K/V staged via global_load_lds into
// [64][64]-short tiles, source-XOR-swizzled (chunk ^= row&7), double-buffered
// with counted vmcnt(3). Interior tiles skip the window mask. Scores arrive
// pre-scaled by 8 (rope_pack). PV: fp16, P scaled x512.
__global__ __launch_bounds__(512, 4) void attn_k(
    const unsigned short* __restrict__ QHL, const unsigned short* __restrict__ KHL,
    const unsigned short* __restrict__ VT, unsigned short* __restrict__ AO)
{
    const int S = 4096;
    const float NEG = -1e30f;
    const float PSC = 512.0f;
    const int bq = blockIdx.x, h = blockIdx.y, b = blockIdx.z;
    const int t = threadIdx.x;
    const int wave = t >> 6, lane = t & 63;
    const int col = lane & 15, quad = lane >> 4;
    const int qg = (bq << 7) + (wave << 4);

    __shared__ __align__(16) short Khs[2][64 * 64];
    __shared__ __align__(16) short Kls[2][64 * 64];
    __shared__ __align__(16) short Vs [2][64 * 64];
    __shared__ __align__(16) short Ps[8][16 * 72];
    short* myP = &Ps[wave][0];

    // staging: wave stages rows [wave*8, wave*8+8); lane l -> row rg, LDS chunk l&7,
    // global chunk (l&7)^rg  =>  LDS[r][c] = global[r][c ^ (r&7)]
    const int rg = lane >> 3;                   // 0..7
    const int ch = (((lane & 7) ^ rg) << 3);    // swizzled source offset (shorts)
    const int srow = (wave << 3) + rg;          // tile row 0..63

    const unsigned short* kbase = KHL + ((size_t)(b * S + srow) << 11) + h * 64 + ch;
    const unsigned short* vbase = VT + ((size_t)((h * 64 + srow) << 1) + b) * S + ch;

#define STAGE(pp, kk)                                          \
    do {                                                       \
        const unsigned short* kr = kbase + ((size_t)(kk) << 11); \
        dma16(kr,        &Khs[pp][wave << 9]);                 \
        dma16(kr + 1024, &Kls[pp][wave << 9]);                 \
        dma16(vbase + (kk), &Vs[pp][wave << 9]);               \
    } while (0)

    short8v qh[2], ql[2];
    {
        const unsigned short* qr = QHL + ((size_t)(b * S + qg + col) << 11) + h * 64 + quad * 8;
        qh[0] = *(const short8v*)(qr);
        qh[1] = *(const short8v*)(qr + 32);
        ql[0] = *(const short8v*)(qr + 1024);
        ql[1] = *(const short8v*)(qr + 1024 + 32);
    }

    float mrun[4], lrun[4], psum[4];
    float4v O[4];
#pragma unroll
    for (int r = 0; r < 4; r++) { mrun[r] = NEG; lrun[r] = 0.f; }
#pragma unroll
    for (int t4 = 0; t4 < 4; t4++) O[t4] = (float4v){0.f, 0.f, 0.f, 0.f};

    const int blk0 = bq << 7;
    const int kstart = (blk0 - 256 > 0) ? (blk0 - 256) : 0;
    const int kend = (blk0 + 384 < S) ? (blk0 + 384) : S;
    const int nt = (kend - kstart) >> 6;

    STAGE(0, kstart);

#pragma unroll 1
    for (int it = 0; it < nt; ++it) {
        const int kb = kstart + (it << 6);
        const int p = it & 1;
        if (it + 1 < nt) { STAGE(p ^ 1, kb + 64); VMW(3); }
        else             { VMW(0); }
        BARF;                       // tile(it) visible in buffer p

        // ---- QK^T (swizzled fragment reads) ----
        const short* KHp = &Khs[p][0];
        const short* KLp = &Kls[p][0];
        float4v sv[4];
        __builtin_amdgcn_s_setprio(1);
#pragma unroll
        for (int c = 0; c < 4; c++) {
            const int row = c * 16 + col;
            const int c0 = ((quad ^ (col & 7)) << 3);
            const int c1 = (((quad + 4) ^ (col & 7)) << 3);
            const short* kro = KHp + (row << 6);
            const short* klo = KLp + (row << 6);
            short8v kh0 = *(const short8v*)(kro + c0);
            short8v kh1 = *(const short8v*)(kro + c1);
            short8v kl0 = *(const short8v*)(klo + c0);
            short8v kl1 = *(const short8v*)(klo + c1);
            float4v sc = (float4v){0.f, 0.f, 0.f, 0.f};
            sc = MFMA_BF16(qh[0], kh0, sc);
            sc = MFMA_BF16(qh[1], kh1, sc);
            sc = MFMA_BF16(qh[0], kl0, sc);
            sc = MFMA_BF16(qh[1], kl1, sc);
            sc = MFMA_BF16(ql[0], kh0, sc);
            sc = MFMA_BF16(ql[1], kh1, sc);
            sv[c] = sc;
        }
        __builtin_amdgcn_s_setprio(0);

        // ---- online softmax ----
        const bool masked = (kb < blk0 - 128) || (kb > blk0 + 192);
        float mx[4];
        if (masked) {
#pragma unroll
            for (int r = 0; r < 4; r++) {
                int qrow = qg + quad * 4 + r;
                float m = NEG;
#pragma unroll
                for (int c = 0; c < 4; c++) {
                    int key = kb + c * 16 + col;
                    float vv = (key >= qrow - 256 && key <= qrow + 256) ? sv[c][r] : NEG;
                    sv[c][r] = vv;
                    m = fmaxf(m, vv);
                }
                mx[r] = m;
            }
        } else {
#pragma unroll
            for (int r = 0; r < 4; r++)
                mx[r] = fmaxf(fmaxf(sv[0][r], sv[1][r]), fmaxf(sv[2][r], sv[3][r]));
        }
#pragma unroll
        for (int st = 1; st < 16; st <<= 1)
#pragma unroll
            for (int r = 0; r < 4; r++) mx[r] = fmaxf(mx[r], __shfl_xor(mx[r], st, 64));

#pragma unroll
        for (int r = 0; r < 4; r++) {
            if (mx[r] > mrun[r]) {            // uniform within each quad's 16 lanes
                float al = __expf(mrun[r] - mx[r]);
                mrun[r] = mx[r];
                lrun[r] *= al;
#pragma unroll
                for (int t4 = 0; t4 < 4; t4++) O[t4][r] *= al;
            }
            float mn = mrun[r];
            float ps = 0.f;
#pragma unroll
            for (int c = 0; c < 4; c++) {
                float pv = __expf(sv[c][r] - mn);
                ps += pv;
                myP[(quad * 4 + r) * 72 + c * 16 + col] =
                    __builtin_bit_cast(short, (_Float16)(pv * PSC));
            }
            psum[r] = ps;
        }
#pragma unroll
        for (int st = 1; st < 16; st <<= 1)
#pragma unroll
            for (int r = 0; r < 4; r++) psum[r] += __shfl_xor(psum[r], st, 64);
#pragma unroll
        for (int r = 0; r < 4; r++) lrun[r] += psum[r];

        // ---- PV (fp16), swizzled V reads ----
        const short* Vp = &Vs[p][0];
        __builtin_amdgcn_s_setprio(1);
#pragma unroll
        for (int kf = 0; kf < 2; kf++) {
            half8v pa = *(const half8v*)(myP + col * 72 + kf * 32 + quad * 8);
#pragma unroll
            for (int t4 = 0; t4 < 4; t4++) {
                const int vrow = t4 * 16 + col;
                const int vc = ((((kf << 2) + quad) ^ (col & 7)) << 3);
                half8v vb = *(const half8v*)(Vp + (vrow << 6) + vc);
                O[t4] = MFMA_F16(pa, vb, O[t4]);
            }
        }
        __builtin_amdgcn_s_setprio(0);

        BARF;                       // all reads of buffer p done -> restageable
    }
#undef STAGE

#pragma unroll
    for (int r = 0; r < 4; r++) {
        float inv = (lrun[r] > 0.f) ? (1.0f / (lrun[r] * PSC)) : 0.f;
        unsigned short* orow = AO + (size_t)(b * S + qg + quad * 4 + r) * 1024 + h * 64;
#pragma unroll
        for (int t4 = 0; t4 < 4; t4++)
            orow[t4 * 16 + col] = __builtin_bit_cast(unsigned short, (_Float16)(O[t4][r] * inv));
    }
}

extern "C" void kernel_launch(void* const* d_in, const int* in_sizes, int n_in,
                              void* d_out, int out_size, void* d_ws, size_t ws_size,
                              hipStream_t stream) {
    const float* q   = (const float*)d_in[0];
    const float* k   = (const float*)d_in[1];
    const float* v   = (const float*)d_in[2];
    const float* wq  = (const float*)d_in[3];
    const float* wk  = (const float*)d_in[4];
    const float* wv  = (const float*)d_in[5];
    const float* wo  = (const float*)d_in[6];
    const float* wob = (const float*)d_in[7];

    float* QP = (float*)d_ws;
    float* KP = QP + (size_t)8192 * 1024;
    unsigned short* VT = (unsigned short*)(KP + (size_t)8192 * 1024);
    unsigned short* AO = VT + (size_t)8192 * 1024;

    // weight scratch inside d_out (final gemm overwrites all of d_out)
    unsigned short* scr = (unsigned short*)d_out;
    const int M1 = 1 << 20;
    const short* wqh = (const short*)(scr);
    const short* wql = (const short*)(scr + M1);
    const short* wkh = (const short*)(scr + 2 * M1);
    const short* wkl = (const short*)(scr + 3 * M1);
    const void*  wv16 = (const void*)(scr + 4 * M1);

    prep_k<<<12288, 256, 0, stream>>>(wq, wk, wv, scr);
    gemm_qk2<<<dim3(256), 512, 0, stream>>>(q, wqh, wql, QP, k, wkh, wkl, KP);
    rope_pack<<<4096, 256, 0, stream>>>(QP, KP);
    gemm16<0, 1, 0><<<dim3(8, 64), 256, 0, stream>>>(v, wv16, (void*)VT, nullptr);
    attn_k<<<dim3(32, 16, 2), 512, 0, stream>>>((const unsigned short*)QP,
                                                (const unsigned short*)KP, VT, AO);
    gemm16<1, 0, 1><<<dim3(8, 64), 256, 0, stream>>>(AO, wo, d_out, wob);
}

// Round 4
// 393.641 us; speedup vs baseline: 1.1613x; 1.0462x over previous
//
#include <hip/hip_runtime.h>

// ---------------------------------------------------------------------------
// SlidingWindowAttention — fp32 in/out.
// Logit path: bf16 hi/lo 3-term MFMA. Split uses INTEGER RNE (immune to
// fp-contraction). Value path: fp16 (V-proj, P, V, AO, out-proj).
//
// gemm_qk2: 256x256 tile, BK=32, 2-barrier counted-vmcnt schedule (R2).
// attn_k:   QBLK=128, dma16 K/V staging + XOR swizzle, dbuf vmcnt(3) (R3).
// gemm16_2 (R4): 128x128 fp16 GEMM with the same counted-vmcnt 2-barrier
// schedule — dbuf LDS (32KB, 2 blocks/CU), vmcnt(6)/vmcnt(2) (never 0 in
// loop), raw s_barrier, cvt staging between MFMA phases, setprio, XCD-chunked
// block swizzle. One operand fp16 via dma16, other fp32 via reg+cvt.
//
// ws (96 MB): QP[0,32) fp32->packed hi/lo | KP[32,64) | VT fp16 [64,80) |
//             AO fp16 [80,96)
// d_out used as scratch for pre-split weights (first 10 MB), overwritten by
// the final out-projection (sole writer of d_out).
// ---------------------------------------------------------------------------

typedef __attribute__((ext_vector_type(8))) short short8v;
typedef __attribute__((ext_vector_type(4))) float float4v;
typedef __attribute__((ext_vector_type(8))) _Float16 half8v;

#define MFMA_BF16(A_, B_, C_) __builtin_amdgcn_mfma_f32_16x16x32_bf16((A_), (B_), (C_), 0, 0, 0)
#define MFMA_F16(A_, B_, C_)  __builtin_amdgcn_mfma_f32_16x16x32_f16((A_), (B_), (C_), 0, 0, 0)

#define VMW_(n) asm volatile("s_waitcnt vmcnt(" #n ")" ::: "memory")
#define VMW(n) VMW_(n)
#define LGKM0 asm volatile("s_waitcnt lgkmcnt(0)" ::: "memory")
#define BARF do { __builtin_amdgcn_s_barrier(); asm volatile("" ::: "memory"); } while (0)
#define FENCE asm volatile("" ::: "memory")

// hi = RNE(x -> bf16) via INTEGER rounding (cannot be contracted/fused);
// lo = x - hi exact in fp32; packed by truncation (err <= 2^-17 |x|).
__device__ __forceinline__ void split_rn(float x, short& h, short& l) {
    unsigned int u = __float_as_uint(x);
    u += 0x7fffu + ((u >> 16) & 1u);          // RNE in integer domain
    unsigned int hb = u & 0xffff0000u;
    h = (short)(hb >> 16);
    float lo = x - __uint_as_float(hb);       // exact (Sterbenz-ish, hi near x)
    l = (short)(__float_as_uint(lo) >> 16);   // truncate lo to bf16
}

// async 16B global -> LDS (wave-uniform LDS base + lane*16)
__device__ __forceinline__ void dma16(const void* g, void* l) {
    __builtin_amdgcn_global_load_lds(
        (__attribute__((address_space(1))) void*)g,
        (__attribute__((address_space(3))) void*)l, 16, 0, 0);
}

// ---------------- prep: weight splits/cvts into d_out scratch ----------------
// scr ushort layout: [0,1M)=wqh [1M,2M)=wql [2M,3M)=wkh [3M,4M)=wkl [4M,5M)=wv16
__global__ __launch_bounds__(256) void prep_k(
    const float* __restrict__ wq, const float* __restrict__ wk,
    const float* __restrict__ wv, unsigned short* __restrict__ scr)
{
    const int M1 = 1 << 20;
    unsigned int tid = blockIdx.x * 256 + threadIdx.x;   // 0 .. 3M-1
    if (tid < (unsigned)M1) {
        short h, l; split_rn(wq[tid], h, l);
        scr[tid] = (unsigned short)h;
        scr[M1 + tid] = (unsigned short)l;
    } else if (tid < (unsigned)(2 * M1)) {
        unsigned int i = tid - M1;
        short h, l; split_rn(wk[i], h, l);
        scr[2 * M1 + i] = (unsigned short)h;
        scr[3 * M1 + i] = (unsigned short)l;
    } else {
        unsigned int i = tid - 2 * M1;
        scr[4 * M1 + i] = __builtin_bit_cast(unsigned short, (_Float16)wv[i]);
    }
}

// ---------------- Q/K projection: C = A * B^T, 3-term bf16 hi/lo ----------------
// 256x256 tile, BK=32, 2-barrier staggered counted-vmcnt schedule.
__global__ __launch_bounds__(512, 2) void gemm_qk2(
    const float* __restrict__ A0, const short* __restrict__ Bh0,
    const short* __restrict__ Bl0, float* __restrict__ C0,
    const float* __restrict__ A1, const short* __restrict__ Bh1,
    const short* __restrict__ Bl1, float* __restrict__ C1)
{
    // LDS: slot p at p*32768 shorts. Within slot (shorts):
    //   Ah +0, Al +8192, Bh +16384, Bl +24576; each array 256 rows x 32 cols.
    __shared__ __align__(16) short S[2 * 32768];   // 128 KiB

    const int bid = blockIdx.x;                 // grid = 256 exactly
    const int cid = ((bid & 7) << 5) | (bid >> 3);
    const int z   = cid >> 7;
    const int rem = cid & 127;
    const int bm  = (rem >> 2) << 8;            // 32 m-blocks * 256
    const int bn  = (rem & 3) << 8;             // 4 n-blocks * 256

    const float* Ap  = z ? A1  : A0;
    const short* Bhp = z ? Bh1 : Bh0;
    const short* Blp = z ? Bl1 : Bl0;
    float*       Cp  = z ? C1  : C0;

    const int t = threadIdx.x;
    const int wave = t >> 6, lane = t & 63;
    const int c16 = lane & 15, quad = lane >> 4;
    const int wm = (wave >> 2) << 7;            // 0 / 128
    const int wn = (wave & 3) << 6;             // 0 / 64 / 128 / 192

    const int ar = t >> 1;                      // 0..255
    const int ah16 = (t & 1) << 4;
    const int fA = (ar & 3) ^ ((ar >> 2) & 3);
    const int swA0 = ((((t & 1) << 1) | 0) ^ fA) << 3;   // shorts
    const int swA1 = ((((t & 1) << 1) | 1) ^ fA) << 3;

    const int br  = lane >> 2;                  // 0..15
    const int fsl = (((lane & 3) ^ ((br & 3) ^ ((br >> 2) & 3))) << 3); // shorts

    const int frd = ((quad ^ ((c16 & 3) ^ ((c16 >> 2) & 3))) << 3);     // shorts

    float4v acc[8][4];
#pragma unroll
    for (int i = 0; i < 8; i++)
#pragma unroll
        for (int j = 0; j < 4; j++) acc[i][j] = (float4v){0.f, 0.f, 0.f, 0.f};

#define STAGE_B(pp, kk)                                                          \
    do {                                                                         \
        const size_t rb = (size_t)(bn + (wave << 5) + br) * 1024 + (kk) + fsl;   \
        short* dh = S + (pp) * 32768 + 16384 + (wave << 10);                     \
        short* dl = dh + 8192;                                                   \
        dma16(Bhp + rb,             dh);                                         \
        dma16(Bhp + rb + 16 * 1024, dh + 512);                                   \
        dma16(Blp + rb,             dl);                                         \
        dma16(Blp + rb + 16 * 1024, dl + 512);                                   \
    } while (0)

#define SPLIT_WRITE(sp_)                                                         \
    do {                                                                         \
        short8v h0, l0, h1, l1;                                                  \
        _Pragma("unroll")                                                        \
        for (int jj = 0; jj < 4; jj++) {                                         \
            short hh, ll;                                                        \
            split_rn(ap0[jj], hh, ll); h0[jj] = hh;     l0[jj] = ll;             \
            split_rn(ap1[jj], hh, ll); h0[jj + 4] = hh; l0[jj + 4] = ll;         \
            split_rn(ap2[jj], hh, ll); h1[jj] = hh;     l1[jj] = ll;             \
            split_rn(ap3[jj], hh, ll); h1[jj + 4] = hh; l1[jj + 4] = ll;         \
        }                                                                        \
        short* abase = (sp_) + ar * 32;                                          \
        *(short8v*)(abase + swA0) = h0;                                          \
        *(short8v*)(abase + swA1) = h1;                                          \
        *(short8v*)(abase + 8192 + swA0) = l0;                                   \
        *(short8v*)(abase + 8192 + swA1) = l1;                                   \
    } while (0)

#define MFMA_CLUSTER(AARR, BARR)                                                 \
    do {                                                                         \
        __builtin_amdgcn_s_setprio(1);                                           \
        _Pragma("unroll")                                                        \
        for (int i = 0; i < 8; i++)                                              \
            _Pragma("unroll")                                                    \
            for (int j = 0; j < 4; j++)                                          \
                acc[i][j] = MFMA_BF16(AARR[i & 7], BARR[j & 3], acc[i][j]);      \
        __builtin_amdgcn_s_setprio(0);                                           \
    } while (0)

    // prologue: A(0) regs first (oldest in vmcnt queue), then B(0) dma -> slot 0
    const float* arow = Ap + (size_t)(bm + ar) * 1024 + ah16;
    float4v ap0 = *(const float4v*)(arow + 0);
    float4v ap1 = *(const float4v*)(arow + 4);
    float4v ap2 = *(const float4v*)(arow + 8);
    float4v ap3 = *(const float4v*)(arow + 12);
    FENCE;                          // pin A(0) loads before B(0) dma in vmcnt queue
    STAGE_B(0, 0);
    VMW(4);                         // A(0) landed (B(0) in flight)
    SPLIT_WRITE(S);                 // -> slot 0 A region
    FENCE;
    ap0 = *(const float4v*)(arow + 32);   // issue A(1)
    ap1 = *(const float4v*)(arow + 36);
    ap2 = *(const float4v*)(arow + 40);
    ap3 = *(const float4v*)(arow + 44);
    LGKM0;                          // split writes done (visible after first barrier)

    // steady-state invariant entering iter tt: vmcnt queue = [B(tt):4, A(tt+1):4]
    int kb = 0;
#pragma unroll 1
    for (int tt = 0; tt < 31; ++tt, kb += 32) {
        short* sp = S + (tt & 1) * 32768;
        short* sn = S + ((tt & 1) ^ 1) * 32768;

        STAGE_B((tt & 1) ^ 1, kb + 32);   // B(tt+1) -> other slot
        VMW(8);                           // B(tt) landed; A(tt+1)+B(tt+1) stay in flight
        BARF;                             // all waves' B(tt) + split A(tt) visible

        // PH1: hi*hi
        short8v ahv[8], bhv[4];
#pragma unroll
        for (int i = 0; i < 8; i++)
            ahv[i] = *(const short8v*)(sp + (wm + i * 16 + c16) * 32 + frd);
#pragma unroll
        for (int j = 0; j < 4; j++)
            bhv[j] = *(const short8v*)(sp + 16384 + (wn + j * 16 + c16) * 32 + frd);
        MFMA_CLUSTER(ahv, bhv);

        // PH2: Ah*Bl (ahv kept in regs; no barrier — Bl(tt) waited at head)
        {
            short8v blv[4];
#pragma unroll
            for (int j = 0; j < 4; j++)
                blv[j] = *(const short8v*)(sp + 24576 + (wn + j * 16 + c16) * 32 + frd);
            MFMA_CLUSTER(ahv, blv);
        }

        // A split for next tile, between MFMA clusters (overlaps matrix pipe)
        VMW(4);                           // A(tt+1) regs landed (B(tt+1) in flight)
        SPLIT_WRITE(sn);
        FENCE;
        {
            int kn = kb + 64;
            if (kn >= 1024) kn = 0;       // tt==30: clamp (junk load, never used)
            ap0 = *(const float4v*)(arow + kn);
            ap1 = *(const float4v*)(arow + kn + 4);
            ap2 = *(const float4v*)(arow + kn + 8);
            ap3 = *(const float4v*)(arow + kn + 12);
        }

        // PH3: Al*Bh (bhv kept in regs)
        {
            short8v alv[8];
#pragma unroll
            for (int i = 0; i < 8; i++)
                alv[i] = *(const short8v*)(sp + 8192 + (wm + i * 16 + c16) * 32 + frd);
            MFMA_CLUSTER(alv, bhv);
        }
        LGKM0;                            // split writes + reads of slot sp done
        BARF;
    }

    // peeled tile 31 (slot 1): queue = [B(31):4, A(32)-junk:4]
    {
        short* sp = S + 32768;
        VMW(4);                           // B(31) landed (junk A may remain)
        BARF;
        short8v ahv[8], bhv[4];
#pragma unroll
        for (int i = 0; i < 8; i++)
            ahv[i] = *(const short8v*)(sp + (wm + i * 16 + c16) * 32 + frd);
#pragma unroll
        for (int j = 0; j < 4; j++)
            bhv[j] = *(const short8v*)(sp + 16384 + (wn + j * 16 + c16) * 32 + frd);
        MFMA_CLUSTER(ahv, bhv);
        {
            short8v blv[4];
#pragma unroll
            for (int j = 0; j < 4; j++)
                blv[j] = *(const short8v*)(sp + 24576 + (wn + j * 16 + c16) * 32 + frd);
            MFMA_CLUSTER(ahv, blv);
        }
        {
            short8v alv[8];
#pragma unroll
            for (int i = 0; i < 8; i++)
                alv[i] = *(const short8v*)(sp + 8192 + (wm + i * 16 + c16) * 32 + frd);
            MFMA_CLUSTER(alv, bhv);
        }
    }

#undef STAGE_B
#undef SPLIT_WRITE
#undef MFMA_CLUSTER

    // epilogue: C/D 16x16: row = quad*4 + r, col = c16
#pragma unroll
    for (int i = 0; i < 8; i++) {
        const size_t gr0 = (size_t)(bm + wm + i * 16 + quad * 4);
#pragma unroll
        for (int j = 0; j < 4; j++) {
            const int gc = bn + wn + j * 16 + c16;
#pragma unroll
            for (int r = 0; r < 4; r++)
                Cp[(gr0 + r) * 1024 + gc] = acc[i][j][r];
        }
    }
}

// ---------------- fp16 GEMM (V-proj / out-proj), C = A * B^T (R4) ----------------
// 128x128 tile, BK=32, 4 waves, dbuf LDS 32KB (2 blocks/CU), counted vmcnt
// (6 at head / 2 mid, never 0 in loop), raw barriers, setprio, XCD swizzle.
// ADMA=1: A fp16 via dma16, B fp32 via reg+cvt (out-proj).
// ADMA=0: A fp32 via reg+cvt, B fp16 via dma16 (V-proj).
// OMODE 0: store fp16 VT transposed. OMODE 1: fp32 + bias -> Cp.
template <int ADMA, int OMODE>
__global__ __launch_bounds__(256, 2) void gemm16_2(
    const void* __restrict__ Ap, const void* __restrict__ Bp,
    void* __restrict__ Cp, const float* __restrict__ bias)
{
    // slot p at p*8192 shorts: As [0,4096), Bs [4096,8192); rows of 32 shorts.
    __shared__ __align__(16) short S[2 * 8192];   // 32 KiB

    const int bid = blockIdx.x;                   // 512 blocks
    const int cid = ((bid & 7) << 6) | (bid >> 3);  // XCD-chunked, bijective
    const int bm  = (cid >> 3) << 7;              // 64 m-blocks
    const int bn  = (cid & 7) << 7;               // 8 n-blocks

    const _Float16* Dp = (const _Float16*)(ADMA ? Ap : Bp);  // dma side (fp16)
    const float*    Fp = (const float*)   (ADMA ? Bp : Ap);  // cvt side (fp32)
    const int bd   = ADMA ? bm : bn;
    const int bf   = ADMA ? bn : bm;
    const int dOff = ADMA ? 0 : 4096;             // dma side LDS region (shorts)
    const int fOff = ADMA ? 4096 : 0;

    const int t = threadIdx.x;
    const int wave = t >> 6, lane = t & 63;
    const int c16 = lane & 15, quad = lane >> 4;
    const int wm = (wave >> 1) << 6;
    const int wn = (wave & 1) << 6;
    const int lr = t >> 2;                        // 0..63
    const int lc = (t & 3) << 3;                  // 0,8,16,24 (elements)

    float4v acc[4][4];
#pragma unroll
    for (int i = 0; i < 4; i++)
#pragma unroll
        for (int j = 0; j < 4; j++) acc[i][j] = (float4v){0.f, 0.f, 0.f, 0.f};

    float4v f00, f01, f10, f11;                   // cvt-side regs (2 rows x 8)

#define STAGE_DMA(pp, kk)                                                        \
    do {                                                                         \
        dma16(Dp + (size_t)(bd + lr) * 1024 + (kk) + lc,                         \
              S + (pp) * 8192 + dOff + (wave << 9));                             \
        dma16(Dp + (size_t)(bd + 64 + lr) * 1024 + (kk) + lc,                    \
              S + (pp) * 8192 + dOff + 2048 + (wave << 9));                      \
    } while (0)

#define LOAD_F(kk)                                                               \
    do {                                                                         \
        FENCE;                                                                   \
        const float* s0_ = Fp + (size_t)(bf + lr) * 1024 + (kk) + lc;            \
        const float* s1_ = Fp + (size_t)(bf + 64 + lr) * 1024 + (kk) + lc;       \
        f00 = *(const float4v*)s0_;  f01 = *(const float4v*)(s0_ + 4);           \
        f10 = *(const float4v*)s1_;  f11 = *(const float4v*)(s1_ + 4);           \
    } while (0)

#define CVT_WRITE(pp)                                                            \
    do {                                                                         \
        half8v h0_, h1_;                                                         \
        _Pragma("unroll")                                                        \
        for (int jj = 0; jj < 4; jj++) {                                         \
            h0_[jj] = (_Float16)f00[jj]; h0_[jj + 4] = (_Float16)f01[jj];        \
            h1_[jj] = (_Float16)f10[jj]; h1_[jj + 4] = (_Float16)f11[jj];        \
        }                                                                        \
        *(half8v*)(S + (pp) * 8192 + fOff + lr * 32 + lc) = h0_;                 \
        *(half8v*)(S + (pp) * 8192 + fOff + (64 + lr) * 32 + lc) = h1_;          \
    } while (0)

    // prologue: cvt(0) regs first (oldest in queue), then dma(0) -> slot 0
    LOAD_F(0);
    STAGE_DMA(0, 0);
    VMW(2);                      // cvt(0) regs landed (dma(0) in flight)
    CVT_WRITE(0);
    LOAD_F(32);                  // issue cvt(1) regs
    LGKM0;                       // cvt writes retired (visible after barrier#1)
    // queue: [dma(0):2, regs(1):4]

#pragma unroll 1
    for (int tt = 0; tt < 31; ++tt) {
        const int kb = tt << 5;
        const int p = tt & 1;
        short* sp = S + p * 8192;

        STAGE_DMA(p ^ 1, kb + 32);   // queue: [dma(t):2, regs(t+1):4, dma(t+1):2]
        VMW(6);                      // dma(t) landed
        BARF;                        // barrier#1: dma(t)+cvt(t) visible everywhere

        half8v ah[4], bh[4];
#pragma unroll
        for (int i = 0; i < 4; i++)
            ah[i] = *(const half8v*)(sp + (wm + i * 16 + c16) * 32 + quad * 8);
#pragma unroll
        for (int j = 0; j < 4; j++)
            bh[j] = *(const half8v*)(sp + 4096 + (wn + j * 16 + c16) * 32 + quad * 8);
        __builtin_amdgcn_s_setprio(1);
#pragma unroll
        for (int i = 0; i < 4; i++)
#pragma unroll
            for (int j = 0; j < 4; j++)
                acc[i][j] = MFMA_F16(ah[i], bh[j], acc[i][j]);
        __builtin_amdgcn_s_setprio(0);

        VMW(2);                      // cvt(t+1) regs landed (dma(t+1) in flight)
        CVT_WRITE(p ^ 1);
        {
            int kn = kb + 64;
            if (kn >= 1024) kn = 0;  // tt==30: junk load, never used
            LOAD_F(kn);              // issue cvt(t+2)
        }
        LGKM0;                       // cvt writes + this wave's frag reads retired
        BARF;                        // barrier#2
    }

    // peeled tile 31 (slot 1): queue = [dma(31):2, regs-junk:4]
    {
        short* sp = S + 8192;
        VMW(4);                      // dma(31) landed
        BARF;
        half8v ah[4], bh[4];
#pragma unroll
        for (int i = 0; i < 4; i++)
            ah[i] = *(const half8v*)(sp + (wm + i * 16 + c16) * 32 + quad * 8);
#pragma unroll
        for (int j = 0; j < 4; j++)
            bh[j] = *(const half8v*)(sp + 4096 + (wn + j * 16 + c16) * 32 + quad * 8);
        __builtin_amdgcn_s_setprio(1);
#pragma unroll
        for (int i = 0; i < 4; i++)
#pragma unroll
            for (int j = 0; j < 4; j++)
                acc[i][j] = MFMA_F16(ah[i], bh[j], acc[i][j]);
        __builtin_amdgcn_s_setprio(0);
    }

#undef STAGE_DMA
#undef LOAD_F
#undef CVT_WRITE

#pragma unroll
    for (int i = 0; i < 4; i++)
#pragma unroll
        for (int j = 0; j < 4; j++)
#pragma unroll
            for (int r = 0; r < 4; r++) {
                int gr = bm + wm + i * 16 + quad * 4 + r;
                int gc = bn + wn + j * 16 + c16;
                float vv = acc[i][j][r];
                if (OMODE == 0) {
                    ((unsigned short*)Cp)[((size_t)(gc << 1) + (gr >> 12)) * 4096 + (gr & 4095)] =
                        __builtin_bit_cast(unsigned short, (_Float16)vv);
                } else {
                    ((float*)Cp)[(size_t)gr * 1024 + gc] = vv + bias[gc];
                }
            }
}

// ---------------- RoPE + in-place hi/lo pack, 4 rows share sincos ----------------
// Q rows (r<2) additionally scaled by 8 = sqrt(dk) — exact (exponent shift).
__global__ __launch_bounds__(256) void rope_pack(float* __restrict__ QP, float* __restrict__ KP)
{
    int sp = blockIdx.x;            // 0..4095
    int t = threadIdx.x;
    float* rows[4] = { QP + ((size_t)sp << 10), QP + ((size_t)(4096 + sp) << 10),
                       KP + ((size_t)sp << 10), KP + ((size_t)(4096 + sp) << 10) };

    float c[2], sn[2];
    float x1[4][2], x2[4][2];
#pragma unroll
    for (int p = 0; p < 2; p++) {
        int j = t + p * 256;
        float freq = __expf(-0.017988946f * (float)j);   // 10000^(-j/512)
        float ang = (float)sp * freq;
        sincosf(ang, &sn[p], &c[p]);
#pragma unroll
        for (int r = 0; r < 4; r++) {
            x1[r][p] = rows[r][j];
            x2[r][p] = rows[r][j + 512];
        }
    }
    __syncthreads();
#pragma unroll
    for (int r = 0; r < 4; r++) {
        unsigned short* u = (unsigned short*)rows[r];
        const float sc8 = (r < 2) ? 8.0f : 1.0f;   // fold sqrt(dk) into Q (exact)
#pragma unroll
        for (int p = 0; p < 2; p++) {
            int j = t + p * 256;
            float y1 = (x1[r][p] * c[p] - x2[r][p] * sn[p]) * sc8;
            float y2 = (x1[r][p] * sn[p] + x2[r][p] * c[p]) * sc8;
            short h1, l1, h2, l2;
            split_rn(y1, h1, l1);
            split_rn(y2, h2, l2);
            u[j] = (unsigned short)h1;
            u[j + 512] = (unsigned short)h2;
            u[1024 + j] = (unsigned short)l1;
            u[1024 + j + 512] = (unsigned short)l2;
        }
    }
}

// ---------------- Banded attention ----------------
// QBLK=128, 8 waves x 16 q-rows. K/V staged via global_load_lds into
// [64][64]-short tiles, source-XOR-swizzled (chunk ^= row&7), double-buffered
// with counted vmcnt(3). Interior tiles skip the window mask. Scores arrive
// pre-scaled by 8 (rope_pack). PV: fp16, P scaled x512.
__global__ __launch_bounds__(512, 4) void attn_k(
    const unsigned short* __restrict__ QHL, const unsigned short* __restrict__ KHL,
    const unsigned short* __restrict__ VT, unsigned short* __restrict__ AO)
{
    const int S = 4096;
    const float NEG = -1e30f;
    const float PSC = 512.0f;
    const int bq = blockIdx.x, h = blockIdx.y, b = blockIdx.z;
    const int t = threadIdx.x;
    const int wave = t >> 6, lane = t & 63;
    const int col = lane & 15, quad = lane >> 4;
    const int qg = (bq << 7) + (wave << 4);

    __shared__ __align__(16) short Khs[2][64 * 64];
    __shared__ __align__(16) short Kls[2][64 * 64];
    __shared__ __align__(16) short Vs [2][64 * 64];
    __shared__ __align__(16) short Ps[8][16 * 72];
    short* myP = &Ps[wave][0];

    const int rg = lane >> 3;                   // 0..7
    const int ch = (((lane & 7) ^ rg) << 3);    // swizzled source offset (shorts)
    const int srow = (wave << 3) + rg;          // tile row 0..63

    const unsigned short* kbase = KHL + ((size_t)(b * S + srow) << 11) + h * 64 + ch;
    const unsigned short* vbase = VT + ((size_t)((h * 64 + srow) << 1) + b) * S + ch;

#define STAGE(pp, kk)                                          \
    do {                                                       \
        const unsigned short* kr = kbase + ((size_t)(kk) << 11); \
        dma16(kr,        &Khs[pp][wave << 9]);                 \
        dma16(kr + 1024, &Kls[pp][wave << 9]);                 \
        dma16(vbase + (kk), &Vs[pp][wave << 9]);               \
    } while (0)

    short8v qh[2], ql[2];
    {
        const unsigned short* qr = QHL + ((size_t)(b * S + qg + col) << 11) + h * 64 + quad * 8;
        qh[0] = *(const short8v*)(qr);
        qh[1] = *(const short8v*)(qr + 32);
        ql[0] = *(const short8v*)(qr + 1024);
        ql[1] = *(const short8v*)(qr + 1024 + 32);
    }

    float mrun[4], lrun[4], psum[4];
    float4v O[4];
#pragma unroll
    for (int r = 0; r < 4; r++) { mrun[r] = NEG; lrun[r] = 0.f; }
#pragma unroll
    for (int t4 = 0; t4 < 4; t4++) O[t4] = (float4v){0.f, 0.f, 0.f, 0.f};

    const int blk0 = bq << 7;
    const int kstart = (blk0 - 256 > 0) ? (blk0 - 256) : 0;
    const int kend = (blk0 + 384 < S) ? (blk0 + 384) : S;
    const int nt = (kend - kstart) >> 6;

    STAGE(0, kstart);

#pragma unroll 1
    for (int it = 0; it < nt; ++it) {
        const int kb = kstart + (it << 6);
        const int p = it & 1;
        if (it + 1 < nt) { STAGE(p ^ 1, kb + 64); VMW(3); }
        else             { VMW(0); }
        BARF;                       // tile(it) visible in buffer p

        // ---- QK^T (swizzled fragment reads) ----
        const short* KHp = &Khs[p][0];
        const short* KLp = &Kls[p][0];
        float4v sv[4];
        __builtin_amdgcn_s_setprio(1);
#pragma unroll
        for (int c = 0; c < 4; c++) {
            const int row = c * 16 + col;
            const int c0 = ((quad ^ (col & 7)) << 3);
            const int c1 = (((quad + 4) ^ (col & 7)) << 3);
            const short* kro = KHp + (row << 6);
            const short* klo = KLp + (row << 6);
            short8v kh0 = *(const short8v*)(kro + c0);
            short8v kh1 = *(const short8v*)(kro + c1);
            short8v kl0 = *(const short8v*)(klo + c0);
            short8v kl1 = *(const short8v*)(klo + c1);
            float4v sc = (float4v){0.f, 0.f, 0.f, 0.f};
            sc = MFMA_BF16(qh[0], kh0, sc);
            sc = MFMA_BF16(qh[1], kh1, sc);
            sc = MFMA_BF16(qh[0], kl0, sc);
            sc = MFMA_BF16(qh[1], kl1, sc);
            sc = MFMA_BF16(ql[0], kh0, sc);
            sc = MFMA_BF16(ql[1], kh1, sc);
            sv[c] = sc;
        }
        __builtin_amdgcn_s_setprio(0);

        // ---- online softmax ----
        const bool masked = (kb < blk0 - 128) || (kb > blk0 + 192);
        float mx[4];
        if (masked) {
#pragma unroll
            for (int r = 0; r < 4; r++) {
                int qrow = qg + quad * 4 + r;
                float m = NEG;
#pragma unroll
                for (int c = 0; c < 4; c++) {
                    int key = kb + c * 16 + col;
                    float vv = (key >= qrow - 256 && key <= qrow + 256) ? sv[c][r] : NEG;
                    sv[c][r] = vv;
                    m = fmaxf(m, vv);
                }
                mx[r] = m;
            }
        } else {
#pragma unroll
            for (int r = 0; r < 4; r++)
                mx[r] = fmaxf(fmaxf(sv[0][r], sv[1][r]), fmaxf(sv[2][r], sv[3][r]));
        }
#pragma unroll
        for (int st = 1; st < 16; st <<= 1)
#pragma unroll
            for (int r = 0; r < 4; r++) mx[r] = fmaxf(mx[r], __shfl_xor(mx[r], st, 64));

#pragma unroll
        for (int r = 0; r < 4; r++) {
            if (mx[r] > mrun[r]) {            // uniform within each quad's 16 lanes
                float al = __expf(mrun[r] - mx[r]);
                mrun[r] = mx[r];
                lrun[r] *= al;
#pragma unroll
                for (int t4 = 0; t4 < 4; t4++) O[t4][r] *= al;
            }
            float mn = mrun[r];
            float ps = 0.f;
#pragma unroll
            for (int c = 0; c < 4; c++) {
                float pv = __expf(sv[c][r] - mn);
                ps += pv;
                myP[(quad * 4 + r) * 72 + c * 16 + col] =
                    __builtin_bit_cast(short, (_Float16)(pv * PSC));
            }
            psum[r] = ps;
        }
#pragma unroll
        for (int st = 1; st < 16; st <<= 1)
#pragma unroll
            for (int r = 0; r < 4; r++) psum[r] += __shfl_xor(psum[r], st, 64);
#pragma unroll
        for (int r = 0; r < 4; r++) lrun[r] += psum[r];

        // ---- PV (fp16), swizzled V reads ----
        const short* Vp = &Vs[p][0];
        __builtin_amdgcn_s_setprio(1);
#pragma unroll
        for (int kf = 0; kf < 2; kf++) {
            half8v pa = *(const half8v*)(myP + col * 72 + kf * 32 + quad * 8);
#pragma unroll
            for (int t4 = 0; t4 < 4; t4++) {
                const int vrow = t4 * 16 + col;
                const int vc = ((((kf << 2) + quad) ^ (col & 7)) << 3);
                half8v vb = *(const half8v*)(Vp + (vrow << 6) + vc);
                O[t4] = MFMA_F16(pa, vb, O[t4]);
            }
        }
        __builtin_amdgcn_s_setprio(0);

        BARF;                       // all reads of buffer p done -> restageable
    }
#undef STAGE

#pragma unroll
    for (int r = 0; r < 4; r++) {
        float inv = (lrun[r] > 0.f) ? (1.0f / (lrun[r] * PSC)) : 0.f;
        unsigned short* orow = AO + (size_t)(b * S + qg + quad * 4 + r) * 1024 + h * 64;
#pragma unroll
        for (int t4 = 0; t4 < 4; t4++)
            orow[t4 * 16 + col] = __builtin_bit_cast(unsigned short, (_Float16)(O[t4][r] * inv));
    }
}

extern "C" void kernel_launch(void* const* d_in, const int* in_sizes, int n_in,
                              void* d_out, int out_size, void* d_ws, size_t ws_size,
                              hipStream_t stream) {
    const float* q   = (const float*)d_in[0];
    const float* k   = (const float*)d_in[1];
    const float* v   = (const float*)d_in[2];
    const float* wq  = (const float*)d_in[3];
    const float* wk  = (const float*)d_in[4];
    const float* wv  = (const float*)d_in[5];
    const float* wo  = (const float*)d_in[6];
    const float* wob = (const float*)d_in[7];

    float* QP = (float*)d_ws;
    float* KP = QP + (size_t)8192 * 1024;
    unsigned short* VT = (unsigned short*)(KP + (size_t)8192 * 1024);
    unsigned short* AO = VT + (size_t)8192 * 1024;

    // weight scratch inside d_out (final gemm overwrites all of d_out)
    unsigned short* scr = (unsigned short*)d_out;
    const int M1 = 1 << 20;
    const short* wqh = (const short*)(scr);
    const short* wql = (const short*)(scr + M1);
    const short* wkh = (const short*)(scr + 2 * M1);
    const short* wkl = (const short*)(scr + 3 * M1);
    const void*  wv16 = (const void*)(scr + 4 * M1);

    prep_k<<<12288, 256, 0, stream>>>(wq, wk, wv, scr);
    gemm_qk2<<<dim3(256), 512, 0, stream>>>(q, wqh, wql, QP, k, wkh, wkl, KP);
    rope_pack<<<4096, 256, 0, stream>>>(QP, KP);
    gemm16_2<0, 0><<<512, 256, 0, stream>>>(v, wv16, (void*)VT, nullptr);
    attn_k<<<dim3(32, 16, 2), 512, 0, stream>>>((const unsigned short*)QP,
                                                (const unsigned short*)KP, VT, AO);
    gemm16_2<1, 1><<<512, 256, 0, stream>>>(AO, wo, d_out, wob);
}